// Round 18
// baseline (512.903 us; speedup 1.0000x reference)
//
#include <hip/hip_runtime.h>
#include <hip/hip_bf16.h>

#define N_LAYERS 2
#define D_MODEL 1024
#define D_INNER 2048
#define D_STATE 16
#define D_CONV 4
#define DT_RANK 64
#define N_CLASSES 10
#define BB 4
#define LL 1024
#define BL (BB*LL)   // 4096 rows
#define CH 32        // scan chunks per sequence
#define CLEN (LL/CH) // 32 steps per chunk
#define KS 8         // split-K segments for x_proj
#define KSO 4        // split-K segments for out_proj (256² pipeline)

typedef __attribute__((ext_vector_type(8))) short bf16x8;
typedef __attribute__((ext_vector_type(8))) unsigned short us8;
typedef __attribute__((ext_vector_type(4))) float f32x4;

typedef const void __attribute__((address_space(1)))* gas_ptr;
typedef void __attribute__((address_space(3)))* las_ptr;
#define GLDS16(g, p) __builtin_amdgcn_global_load_lds((gas_ptr)(g), (las_ptr)(p), 16, 0, 0)

__device__ inline unsigned short rnd_bf16(float x) {
  unsigned u = __float_as_uint(x);
  return (unsigned short)((u + 0x7FFFu + ((u >> 16) & 1u)) >> 16);
}
__device__ inline float b2f(unsigned short u) {
  return __uint_as_float(((unsigned)u) << 16);
}

// round weights to bf16
__global__ __launch_bounds__(256) void round_k(const float* __restrict__ in,
    unsigned short* __restrict__ hi) {
  const int i = blockIdx.x * 256 + threadIdx.x;
  const float4 v = ((const float4*)in)[i];
  ushort4 h4;
  h4.x = rnd_bf16(v.x); h4.y = rnd_bf16(v.y);
  h4.z = rnd_bf16(v.z); h4.w = rnd_bf16(v.w);
  ((ushort4*)hi)[i] = h4;
}

// ---------------- LayerNorm -> bf16 out ---------------------------------------
__global__ __launch_bounds__(256) void layernorm_bf16_k(const float* __restrict__ x,
    const float* __restrict__ w, const float* __restrict__ b,
    unsigned short* __restrict__ oh) {
  const int row = blockIdx.x;
  const int t = threadIdx.x;
  const float4 v = *(const float4*)(x + (size_t)row * D_MODEL + t * 4);
  float s = v.x + v.y + v.z + v.w;
  float q = v.x*v.x + v.y*v.y + v.z*v.z + v.w*v.w;
  #pragma unroll
  for (int o = 32; o; o >>= 1) { s += __shfl_down(s, o); q += __shfl_down(q, o); }
  __shared__ float red[8];
  if ((t & 63) == 0) { red[t >> 6] = s; red[4 + (t >> 6)] = q; }
  __syncthreads();
  s = red[0] + red[1] + red[2] + red[3];
  q = red[4] + red[5] + red[6] + red[7];
  const float mean = s * (1.f / D_MODEL);
  const float var  = q * (1.f / D_MODEL) - mean * mean;
  const float rstd = rsqrtf(var + 1e-5f);
  const float4 wv = *(const float4*)(w + t * 4);
  const float4 bv = *(const float4*)(b + t * 4);
  ushort4 h4;
  h4.x = rnd_bf16((v.x - mean) * rstd * wv.x + bv.x);
  h4.y = rnd_bf16((v.y - mean) * rstd * wv.y + bv.y);
  h4.z = rnd_bf16((v.z - mean) * rstd * wv.z + bv.z);
  h4.w = rnd_bf16((v.w - mean) * rstd * wv.w + bv.w);
  ((ushort4*)(oh + (size_t)row * D_MODEL))[t] = h4;
}

// ---- fused: Xout = Xin + sum(out_proj partials); then LayerNorm -> operand ---
template<int OUT>
__global__ __launch_bounds__(256) void oreduce_ln_k(
    const float* __restrict__ part, const float* __restrict__ Xin,
    float* __restrict__ Xout,
    const float* __restrict__ w, const float* __restrict__ b,
    void* __restrict__ out) {
  const int row = blockIdx.x;
  const int t = threadIdx.x;
  float4 v = *(const float4*)(Xin + (size_t)row * D_MODEL + t * 4);
  #pragma unroll
  for (int k = 0; k < KSO; k++) {
    const float4 p = *(const float4*)(part + (size_t)k * BL * D_MODEL
                                      + (size_t)row * D_MODEL + t * 4);
    v.x += p.x; v.y += p.y; v.z += p.z; v.w += p.w;
  }
  *(float4*)(Xout + (size_t)row * D_MODEL + t * 4) = v;   // residual stream
  float s = v.x + v.y + v.z + v.w;
  float q = v.x*v.x + v.y*v.y + v.z*v.z + v.w*v.w;
  #pragma unroll
  for (int o = 32; o; o >>= 1) { s += __shfl_down(s, o); q += __shfl_down(q, o); }
  __shared__ float red[8];
  if ((t & 63) == 0) { red[t >> 6] = s; red[4 + (t >> 6)] = q; }
  __syncthreads();
  s = red[0] + red[1] + red[2] + red[3];
  q = red[4] + red[5] + red[6] + red[7];
  const float mean = s * (1.f / D_MODEL);
  const float var  = q * (1.f / D_MODEL) - mean * mean;
  const float rstd = rsqrtf(var + 1e-5f);
  const float4 wv = *(const float4*)(w + t * 4);
  const float4 bv = *(const float4*)(b + t * 4);
  float4 o4;
  o4.x = (v.x - mean) * rstd * wv.x + bv.x;
  o4.y = (v.y - mean) * rstd * wv.y + bv.y;
  o4.z = (v.z - mean) * rstd * wv.z + bv.z;
  o4.w = (v.w - mean) * rstd * wv.w + bv.w;
  if constexpr (OUT == 0) {
    ushort4 h4;
    h4.x = rnd_bf16(o4.x); h4.y = rnd_bf16(o4.y);
    h4.z = rnd_bf16(o4.z); h4.w = rnd_bf16(o4.w);
    ((ushort4*)((unsigned short*)out + (size_t)row * D_MODEL))[t] = h4;
  } else {
    *(float4*)((float*)out + (size_t)row * D_MODEL + t * 4) = o4;
  }
}

// ==== 256x256 bf16 MFMA GEMM NT — counted-vmcnt pipeline =====================
// EPI 0: bf16 C. EPI 1: fp32 partials at C + bz*M*ldc (split-K).
// REMAP 1: XCD panel remap (requires grid 16x16). 2 K-tile prefetch, vmcnt(8),
// raw barriers, T2 read swizzle pre-applied to global source. 128 KB LDS.
template<int EPI, int KSEG, int REMAP>
__global__ __launch_bounds__(512) void mfma_gemm256_nt(
    const unsigned short* __restrict__ A, const unsigned short* __restrict__ B,
    void* __restrict__ Cv, int M, int N, int K, int ldc) {
  __shared__ unsigned short S[65536];   // [buf:2][mat:2][256*64] bf16 = 128 KB
  const int tid = threadIdx.x;
  const int l = tid & 63;
  const int w = tid >> 6;
  const int wm = w >> 2, wn = w & 3;
  int bx, by;
  if constexpr (REMAP == 1) {
    const int bid = blockIdx.y * 16 + blockIdx.x;
    const int x = bid & 7, v = bid >> 3;
    bx = (x & 1) * 8 + (v & 7);
    by = (x >> 1) * 4 + (v >> 3);
  } else {
    bx = blockIdx.x; by = blockIdx.y;
  }
  const int m0 = by * 256, n0 = bx * 256;
  const int kseg = K / KSEG;
  const int kbeg = (KSEG > 1) ? blockIdx.z * kseg : 0;
  const int nkt = kseg >> 6;
  const int r8 = (tid >> 3) & 7;
  const int c16s = (tid & 7) ^ r8;                // pre-swizzled source col16

  auto stage1 = [&](int kt, int mat, int half) {
    const unsigned short* base = (mat == 0) ? (A + (size_t)m0 * K)
                                            : (B + (size_t)n0 * K);
    unsigned short* dst = S + ((kt & 1) * 32768 + mat * 16384 + half * 8192);
    #pragma unroll
    for (int e = 0; e < 2; ++e) {
      const int row = half * 128 + e * 64 + (tid >> 3);
      GLDS16(base + (size_t)row * K + kbeg + kt * 64 + c16s * 8,
             dst + e * 4096 + tid * 8);
    }
  };
  auto stage_full = [&](int kt) {
    stage1(kt, 0, 0); stage1(kt, 0, 1); stage1(kt, 1, 0); stage1(kt, 1, 1);
  };

  stage_full(0);
  if (nkt > 1) stage_full(1);

  f32x4 acc[8][4] = {};
  const int fr = l & 15;
  const int fk8 = l >> 4;

  #pragma unroll 1
  for (int kt = 0; kt < nkt; ++kt) {
    if (kt + 1 < nkt) asm volatile("s_waitcnt vmcnt(8)" ::: "memory");
    else              asm volatile("s_waitcnt vmcnt(0)" ::: "memory");
    __builtin_amdgcn_s_barrier();
    __builtin_amdgcn_sched_barrier(0);
    const unsigned short* SA = S + (kt & 1) * 32768;
    const unsigned short* SB = SA + 16384;
    bf16x8 av[8], bv[4];
    // half 0: read + MFMA
    {
      const int c8 = fk8;
      #pragma unroll
      for (int i = 0; i < 8; ++i) {
        const int R = wm * 128 + i * 16 + fr;
        av[i] = *(const bf16x8*)&SA[R * 64 + ((c8 ^ (R & 7)) << 3)];
      }
      #pragma unroll
      for (int j = 0; j < 4; ++j) {
        const int R = wn * 64 + j * 16 + fr;
        bv[j] = *(const bf16x8*)&SB[R * 64 + ((c8 ^ (R & 7)) << 3)];
      }
      __builtin_amdgcn_s_setprio(1);
      #pragma unroll
      for (int i = 0; i < 8; ++i)
        #pragma unroll
        for (int j = 0; j < 4; ++j)
          acc[i][j] = __builtin_amdgcn_mfma_f32_16x16x32_bf16(
              av[i], bv[j], acc[i][j], 0, 0, 0);
      __builtin_amdgcn_s_setprio(0);
    }
    // half 1: read, then free the LDS buffer (barrier) before its MFMA so
    // stage(kt+2) issue overlaps the register-only MFMA burst.
    {
      const int c8 = 4 + fk8;
      #pragma unroll
      for (int i = 0; i < 8; ++i) {
        const int R = wm * 128 + i * 16 + fr;
        av[i] = *(const bf16x8*)&SA[R * 64 + ((c8 ^ (R & 7)) << 3)];
      }
      #pragma unroll
      for (int j = 0; j < 4; ++j) {
        const int R = wn * 64 + j * 16 + fr;
        bv[j] = *(const bf16x8*)&SB[R * 64 + ((c8 ^ (R & 7)) << 3)];
      }
      asm volatile("s_waitcnt lgkmcnt(0)" ::: "memory");
      __builtin_amdgcn_s_barrier();                 // all waves done reading
      __builtin_amdgcn_sched_barrier(0);
      if (kt + 2 < nkt) stage_full(kt + 2);         // overwrite freed buffer
      __builtin_amdgcn_s_setprio(1);
      #pragma unroll
      for (int i = 0; i < 8; ++i)
        #pragma unroll
        for (int j = 0; j < 4; ++j)
          acc[i][j] = __builtin_amdgcn_mfma_f32_16x16x32_bf16(
              av[i], bv[j], acc[i][j], 0, 0, 0);
      __builtin_amdgcn_s_setprio(0);
    }
  }

  const int orow = (l >> 4) * 4, ocol = l & 15;
  if constexpr (EPI == 0) {
    unsigned short* C = (unsigned short*)Cv;
    #pragma unroll
    for (int i = 0; i < 8; ++i)
      #pragma unroll
      for (int j = 0; j < 4; ++j)
        #pragma unroll
        for (int r = 0; r < 4; ++r) {
          const int m = m0 + wm * 128 + i * 16 + orow + r;
          const int n = n0 + wn * 64 + j * 16 + ocol;
          C[(size_t)m * ldc + n] = rnd_bf16(acc[i][j][r]);
        }
  } else {
    float* C = (float*)Cv + (size_t)blockIdx.z * M * ldc;
    #pragma unroll
    for (int i = 0; i < 8; ++i)
      #pragma unroll
      for (int j = 0; j < 4; ++j)
        #pragma unroll
        for (int r = 0; r < 4; ++r) {
          const int m = m0 + wm * 128 + i * 16 + orow + r;
          const int n = n0 + wn * 64 + j * 16 + ocol;
          C[(size_t)m * ldc + n] = acc[i][j][r];
        }
  }
}

// ---- bf16 MFMA GEMM NT 128² (dt GEMM) ----------------------------------------
// EPI 2: softplus+bias -> bf16.
template<int EPI, int KSEG>
__global__ __launch_bounds__(256) void mfma_gemm_nt(
    const unsigned short* __restrict__ Ah, const unsigned short* __restrict__ Bh,
    void* __restrict__ Cv, int M, int N, int K, int ldc,
    const float* __restrict__ bias) {
  __shared__ unsigned short As[128 * 64];
  __shared__ unsigned short Bs[128 * 64];
  const int tid = threadIdx.x;
  const int w = tid >> 6, l = tid & 63;
  const int wr = w >> 1, wc = w & 1;
  const int nbx = gridDim.x;
  const int nwg = nbx * gridDim.y;
  int bid = blockIdx.y * nbx + blockIdx.x;
  bid = (bid & 7) * (nwg >> 3) + (bid >> 3);
  const int st = bid >> 6, wi = bid & 63;
  const int stpr = (nbx >= 8) ? (nbx >> 3) : 1;
  int n0, m0;
  if (nbx >= 8) {
    n0 = ((st % stpr) * 8 + (wi & 7)) * 128;
    m0 = ((st / stpr) * 8 + (wi >> 3)) * 128;
  } else {
    n0 = (bid % nbx) * 128;
    m0 = (bid / nbx) * 128;
  }
  const int kz = (KSEG > 1) ? blockIdx.z : 0;
  const int kbeg = kz * (K / KSEG);
  const int kend = kbeg + K / KSEG;
  const int srow = l >> 3;
  const int scol = (l & 7) * 8;
  const int fr = l & 15;
  const int fk = (l >> 4) * 8;
  f32x4 acc[4][4] = {};

  #pragma unroll 1
  for (int k0 = kbeg; k0 < kend; k0 += 64) {
    __syncthreads();
    #pragma unroll
    for (int it = 0; it < 4; ++it) {
      const int bi = it * 4 + w;
      const int row = bi * 8 + srow;
      GLDS16(Ah + (size_t)(m0 + row) * K + k0 + scol, &As[bi * 512 + l * 8]);
      GLDS16(Bh + (size_t)(n0 + row) * K + k0 + scol, &Bs[bi * 512 + l * 8]);
    }
    __syncthreads();
    #pragma unroll
    for (int kk = 0; kk < 64; kk += 32) {
      bf16x8 a[4], b[4];
      #pragma unroll
      for (int f = 0; f < 4; ++f)
        b[f] = *(const bf16x8*)&Bs[(wc * 64 + f * 16 + fr) * 64 + kk + fk];
      #pragma unroll
      for (int f = 0; f < 4; ++f)
        a[f] = *(const bf16x8*)&As[(wr * 64 + f * 16 + fr) * 64 + kk + fk];
      #pragma unroll
      for (int i = 0; i < 4; ++i)
        #pragma unroll
        for (int j = 0; j < 4; ++j)
          acc[i][j] = __builtin_amdgcn_mfma_f32_16x16x32_bf16(
              a[i], b[j], acc[i][j], 0, 0, 0);
    }
  }
  const int orow = (l >> 4) * 4;
  const int ocol = l & 15;
  if constexpr (EPI == 0 || EPI == 2) {
    unsigned short* Cw = (unsigned short*)Cv;
    #pragma unroll
    for (int i = 0; i < 4; ++i)
      #pragma unroll
      for (int j = 0; j < 4; ++j)
        #pragma unroll
        for (int r = 0; r < 4; ++r) {
          const int m = m0 + wr * 64 + i * 16 + orow + r;
          const int n = n0 + wc * 64 + j * 16 + ocol;
          float vv = acc[i][j][r];
          if constexpr (EPI == 2) {
            vv += bias[n];
            vv = (vv > 20.f) ? vv : log1pf(__expf(vv));
          }
          Cw[(size_t)m * ldc + n] = rnd_bf16(vv);
        }
  } else {
    float* Cw = (float*)Cv + (size_t)kz * M * ldc;
    #pragma unroll
    for (int i = 0; i < 4; ++i)
      #pragma unroll
      for (int j = 0; j < 4; ++j)
        #pragma unroll
        for (int r = 0; r < 4; ++r) {
          const int m = m0 + wr * 64 + i * 16 + orow + r;
          const int n = n0 + wc * 64 + j * 16 + ocol;
          Cw[(size_t)m * ldc + n] = acc[i][j][r];
        }
  }
}

// ---- x_proj split-K (bf16 A) ------------------------------------------------
__global__ __launch_bounds__(256) void sgemm_splitk_k(
    const unsigned short* __restrict__ A, const float* __restrict__ B,
    float* __restrict__ part) {
  __shared__ float As[32][64 + 4];
  __shared__ float Bs[32][32 + 4];
  const int tid = threadIdx.x;
  const int n0 = blockIdx.x * 32;
  const int m0 = blockIdx.y * 64;
  const int kz = blockIdx.z;
  const int tn = (tid & 15) * 2;
  const int tm = (tid >> 4) * 4;
  float acc[4][2] = {};
  for (int kb = 0; kb < 256; kb += 32) {
    const int k0 = kz * 256 + kb;
    {
      int r = tid >> 2, c8 = (tid & 3) * 8;
      us8 u = *(const us8*)(A + (size_t)(m0 + r) * D_INNER + k0 + c8);
      #pragma unroll
      for (int j = 0; j < 8; j++) As[c8 + j][r] = b2f((unsigned short)u[j]);
    }
    {
      int r = tid >> 3, c4 = tid & 7;
      float4 v = *(const float4*)(B + (size_t)(n0 + r) * D_INNER + k0 + c4 * 4);
      Bs[c4*4+0][r] = v.x; Bs[c4*4+1][r] = v.y;
      Bs[c4*4+2][r] = v.z; Bs[c4*4+3][r] = v.w;
    }
    __syncthreads();
    #pragma unroll
    for (int k = 0; k < 32; k++) {
      float a[4], bf[2];
      #pragma unroll
      for (int i = 0; i < 4; i++) a[i] = As[k][tm + i];
      bf[0] = Bs[k][tn]; bf[1] = Bs[k][tn + 1];
      #pragma unroll
      for (int i = 0; i < 4; i++) {
        acc[i][0] = fmaf(a[i], bf[0], acc[i][0]);
        acc[i][1] = fmaf(a[i], bf[1], acc[i][1]);
      }
    }
    __syncthreads();
  }
  float* p = part + (size_t)kz * BL * 96;
  #pragma unroll
  for (int i = 0; i < 4; i++) {
    const int m = m0 + tm + i;
    p[(size_t)m * 96 + n0 + tn]     = acc[i][0];
    p[(size_t)m * 96 + n0 + tn + 1] = acc[i][1];
  }
}

// reduce KS partials; split: cols 0..63 -> bf16 dtr, 64..95 -> fp32 bc[BL][32]
__global__ __launch_bounds__(256) void xproj_reduce_k(
    const float* __restrict__ part, unsigned short* __restrict__ dtr,
    float* __restrict__ bc) {
  const int i = blockIdx.x * 256 + threadIdx.x;   // over BL*96
  const int m = i / 96, col = i % 96;
  float s = 0.f;
  #pragma unroll
  for (int k = 0; k < KS; k++) s += part[(size_t)k * BL * 96 + i];
  if (col < DT_RANK) dtr[(size_t)m * DT_RANK + col] = rnd_bf16(s);
  else               bc[(size_t)m * 32 + (col - DT_RANK)] = s;
}

// ------ causal depthwise conv + SiLU, bf16 in / bf16 out ----------------------
__global__ __launch_bounds__(256) void conv_silu_k(
    const unsigned short* __restrict__ xz,
    const float* __restrict__ cw, const float* __restrict__ cb,
    unsigned short* __restrict__ xc) {
  const int gid = blockIdx.x * 256 + threadIdx.x;
  const int c4 = (gid & (D_INNER / 4 - 1)) << 2;
  const int row = gid >> 9;
  const int l = row & (LL - 1);
  const unsigned short* base = xz + (size_t)row * (2 * D_INNER) + c4;
  const float4 w0 = *(const float4*)(cw + (c4 + 0) * 4);
  const float4 w1 = *(const float4*)(cw + (c4 + 1) * 4);
  const float4 w2 = *(const float4*)(cw + (c4 + 2) * 4);
  const float4 w3 = *(const float4*)(cw + (c4 + 3) * 4);
  float4 acc = *(const float4*)(cb + c4);
  ushort4 uv = *(const ushort4*)base;
  acc.x = fmaf(w0.w, b2f(uv.x), acc.x); acc.y = fmaf(w1.w, b2f(uv.y), acc.y);
  acc.z = fmaf(w2.w, b2f(uv.z), acc.z); acc.w = fmaf(w3.w, b2f(uv.w), acc.w);
  if (l >= 1) {
    uv = *(const ushort4*)(base - 2 * D_INNER);
    acc.x = fmaf(w0.z, b2f(uv.x), acc.x); acc.y = fmaf(w1.z, b2f(uv.y), acc.y);
    acc.z = fmaf(w2.z, b2f(uv.z), acc.z); acc.w = fmaf(w3.z, b2f(uv.w), acc.w);
  }
  if (l >= 2) {
    uv = *(const ushort4*)(base - 4 * D_INNER);
    acc.x = fmaf(w0.y, b2f(uv.x), acc.x); acc.y = fmaf(w1.y, b2f(uv.y), acc.y);
    acc.z = fmaf(w2.y, b2f(uv.z), acc.z); acc.w = fmaf(w3.y, b2f(uv.w), acc.w);
  }
  if (l >= 3) {
    uv = *(const ushort4*)(base - 6 * D_INNER);
    acc.x = fmaf(w0.x, b2f(uv.x), acc.x); acc.y = fmaf(w1.x, b2f(uv.y), acc.y);
    acc.z = fmaf(w2.x, b2f(uv.z), acc.z); acc.w = fmaf(w3.x, b2f(uv.w), acc.w);
  }
  ushort4 o4;
  o4.x = rnd_bf16(acc.x / (1.f + __expf(-acc.x)));
  o4.y = rnd_bf16(acc.y / (1.f + __expf(-acc.y)));
  o4.z = rnd_bf16(acc.z / (1.f + __expf(-acc.z)));
  o4.w = rnd_bf16(acc.w / (1.f + __expf(-acc.w)));
  *(ushort4*)(xc + (size_t)row * D_INNER + c4) = o4;
}

// w-power helper: P[n] = w^(n+1), depth-4 multiply tree
__device__ inline void wpowers(float w1, float* P) {
  const float w2 = w1 * w1, w3 = w2 * w1, w4 = w2 * w2;
  const float w5 = w4 * w1, w6 = w4 * w2, w7 = w4 * w3, w8 = w4 * w4;
  P[0] = w1;  P[1] = w2;  P[2] = w3;  P[3] = w4;
  P[4] = w5;  P[5] = w6;  P[6] = w7;  P[7] = w8;
  P[8]  = w8 * w1;  P[9]  = w8 * w2;  P[10] = w8 * w3;  P[11] = w8 * w4;
  P[12] = w8 * w5;  P[13] = w8 * w6;  P[14] = w8 * w7;  P[15] = w8 * w8;
}

// ------- chunked selective scan, pass 1 (bf16 dt/xc, bc stride 32) ------------
__global__ __launch_bounds__(256) void scan_pass1_k(
    const unsigned short* __restrict__ dt, const unsigned short* __restrict__ xc,
    const float* __restrict__ bc, const float* __restrict__ A_log,
    float* __restrict__ hend, float* __restrict__ sumdt) {
  const int c = blockIdx.x * 256 + threadIdx.x;
  const int k = blockIdx.y;
  const int b = blockIdx.z;
  float Ac[D_STATE];
  bool fast = true;
  #pragma unroll
  for (int n = 0; n < D_STATE; n++) {
    Ac[n] = -__expf(A_log[c * D_STATE + n]);
    fast = fast && (fabsf(Ac[n] + (float)(n + 1)) <= 4e-6f * (float)(n + 1));
  }
  float h[D_STATE] = {};
  float sd = 0.f;
  const size_t r0 = (size_t)b * LL + (size_t)k * CLEN;
  const unsigned short* dtp = dt + r0 * D_INNER + c;
  const unsigned short* xcp = xc + r0 * D_INNER + c;
  const float* Bp  = bc + r0 * 32;

  float dtv = b2f(dtp[0]);
  float xv  = b2f(xcp[0]);
  float4 B0 = *(const float4*)(Bp + 0);
  float4 B1 = *(const float4*)(Bp + 4);
  float4 B2 = *(const float4*)(Bp + 8);
  float4 B3 = *(const float4*)(Bp + 12);
  if (fast) {
    for (int l = 0; l < CLEN; l++) {
      const int lp = (l + 1 < CLEN) ? l + 1 : l;
      const float dtv2 = b2f(dtp[(size_t)lp * D_INNER]);
      const float xv2  = b2f(xcp[(size_t)lp * D_INNER]);
      const float4 B0n = *(const float4*)(Bp + (size_t)lp * 32 + 0);
      const float4 B1n = *(const float4*)(Bp + (size_t)lp * 32 + 4);
      const float4 B2n = *(const float4*)(Bp + (size_t)lp * 32 + 8);
      const float4 B3n = *(const float4*)(Bp + (size_t)lp * 32 + 12);
      sd += dtv;
      const float dx = dtv * xv;
      float P[D_STATE];
      wpowers(__expf(-dtv), P);
      const float Bv[D_STATE] = {B0.x,B0.y,B0.z,B0.w, B1.x,B1.y,B1.z,B1.w,
                                 B2.x,B2.y,B2.z,B2.w, B3.x,B3.y,B3.z,B3.w};
      #pragma unroll
      for (int n = 0; n < D_STATE; n++)
        h[n] = fmaf(P[n], h[n], dx * Bv[n]);
      dtv = dtv2; xv = xv2; B0 = B0n; B1 = B1n; B2 = B2n; B3 = B3n;
    }
  } else {
    for (int l = 0; l < CLEN; l++) {
      const int lp = (l + 1 < CLEN) ? l + 1 : l;
      const float dtv2 = b2f(dtp[(size_t)lp * D_INNER]);
      const float xv2  = b2f(xcp[(size_t)lp * D_INNER]);
      const float4 B0n = *(const float4*)(Bp + (size_t)lp * 32 + 0);
      const float4 B1n = *(const float4*)(Bp + (size_t)lp * 32 + 4);
      const float4 B2n = *(const float4*)(Bp + (size_t)lp * 32 + 8);
      const float4 B3n = *(const float4*)(Bp + (size_t)lp * 32 + 12);
      sd += dtv;
      const float dx = dtv * xv;
      const float Bv[D_STATE] = {B0.x,B0.y,B0.z,B0.w, B1.x,B1.y,B1.z,B1.w,
                                 B2.x,B2.y,B2.z,B2.w, B3.x,B3.y,B3.z,B3.w};
      #pragma unroll
      for (int n = 0; n < D_STATE; n++)
        h[n] = fmaf(__expf(dtv * Ac[n]), h[n], dx * Bv[n]);
      dtv = dtv2; xv = xv2; B0 = B0n; B1 = B1n; B2 = B2n; B3 = B3n;
    }
  }
  float* he = hend + (((size_t)(b * CH + k) * D_INNER + c) << 4);
  #pragma unroll
  for (int n = 0; n < D_STATE; n += 4)
    *(float4*)(he + n) = make_float4(h[n], h[n+1], h[n+2], h[n+3]);
  sumdt[(size_t)(b * CH + k) * D_INNER + c] = sd;
}

// ------- chunked scan fixup ---------------------------------------------------
__global__ __launch_bounds__(256) void scan_fix_k(
    float* __restrict__ hend, const float* __restrict__ sumdt,
    const float* __restrict__ A_log) {
  const int gid = blockIdx.x * 256 + threadIdx.x;
  const int n = gid & 15;
  const int c = (gid >> 4) & (D_INNER - 1);
  const int b = gid >> 15;
  const float Ac = -__expf(A_log[c * D_STATE + n]);
  float hrun = 0.f;
  for (int k = 0; k < CH; k++) {
    const size_t base = (size_t)(b * CH + k) * D_INNER + c;
    const float sd = sumdt[base];
    float* hp = hend + (base << 4) + n;
    const float tmp = *hp;
    *hp = hrun;
    hrun = fmaf(__expf(Ac * sd), hrun, tmp);
  }
}

// ------- chunked scan pass 3 (bc stride 32, fast w-power path) -----------------
__global__ __launch_bounds__(256) void scan_pass3_k(
    const unsigned short* __restrict__ dt, const unsigned short* __restrict__ xc,
    const float* __restrict__ bc, const unsigned short* __restrict__ xz,
    const float* __restrict__ h0, const float* __restrict__ A_log,
    const float* __restrict__ Dp, unsigned short* __restrict__ yh) {
  const int c = blockIdx.x * 256 + threadIdx.x;
  const int k = blockIdx.y;
  const int b = blockIdx.z;
  float Ac[D_STATE];
  bool fast = true;
  #pragma unroll
  for (int n = 0; n < D_STATE; n++) {
    Ac[n] = -__expf(A_log[c * D_STATE + n]);
    fast = fast && (fabsf(Ac[n] + (float)(n + 1)) <= 4e-6f * (float)(n + 1));
  }
  const float Dv = Dp[c];
  float h[D_STATE];
  const float* hp = h0 + (((size_t)(b * CH + k) * D_INNER + c) << 4);
  #pragma unroll
  for (int n = 0; n < D_STATE; n += 4) {
    const float4 v = *(const float4*)(hp + n);
    h[n] = v.x; h[n+1] = v.y; h[n+2] = v.z; h[n+3] = v.w;
  }
  const size_t r0 = (size_t)b * LL + (size_t)k * CLEN;
  const unsigned short* dtp = dt + r0 * D_INNER + c;
  const unsigned short* xcp = xc + r0 * D_INNER + c;
  const float* Bp  = bc + r0 * 32;
  const unsigned short* zp = xz + r0 * (size_t)(2 * D_INNER) + D_INNER + c;
  unsigned short* yhp = yh + r0 * D_INNER + c;

  float dtv = b2f(dtp[0]);
  float xv  = b2f(xcp[0]);
  float zv  = b2f(zp[0]);
  float4 B0 = *(const float4*)(Bp + 0);
  float4 B1 = *(const float4*)(Bp + 4);
  float4 B2 = *(const float4*)(Bp + 8);
  float4 B3 = *(const float4*)(Bp + 12);
  float4 C0 = *(const float4*)(Bp + 16);
  float4 C1 = *(const float4*)(Bp + 20);
  float4 C2 = *(const float4*)(Bp + 24);
  float4 C3 = *(const float4*)(Bp + 28);
  if (fast) {
    for (int l = 0; l < CLEN; l++) {
      const int lp = (l + 1 < CLEN) ? l + 1 : l;
      const float dtv2 = b2f(dtp[(size_t)lp * D_INNER]);
      const float xv2  = b2f(xcp[(size_t)lp * D_INNER]);
      const float zv2  = b2f(zp[(size_t)lp * 2 * D_INNER]);
      const float4 B0n = *(const float4*)(Bp + (size_t)lp * 32 + 0);
      const float4 B1n = *(const float4*)(Bp + (size_t)lp * 32 + 4);
      const float4 B2n = *(const float4*)(Bp + (size_t)lp * 32 + 8);
      const float4 B3n = *(const float4*)(Bp + (size_t)lp * 32 + 12);
      const float4 C0n = *(const float4*)(Bp + (size_t)lp * 32 + 16);
      const float4 C1n = *(const float4*)(Bp + (size_t)lp * 32 + 20);
      const float4 C2n = *(const float4*)(Bp + (size_t)lp * 32 + 24);
      const float4 C3n = *(const float4*)(Bp + (size_t)lp * 32 + 28);
      const float dx = dtv * xv;
      float P[D_STATE];
      wpowers(__expf(-dtv), P);
      const float Bv[D_STATE] = {B0.x,B0.y,B0.z,B0.w, B1.x,B1.y,B1.z,B1.w,
                                 B2.x,B2.y,B2.z,B2.w, B3.x,B3.y,B3.z,B3.w};
      const float Cv[D_STATE] = {C0.x,C0.y,C0.z,C0.w, C1.x,C1.y,C1.z,C1.w,
                                 C2.x,C2.y,C2.z,C2.w, C3.x,C3.y,C3.z,C3.w};
      float y = 0.f;
      #pragma unroll
      for (int n = 0; n < D_STATE; n++) {
        h[n] = fmaf(P[n], h[n], dx * Bv[n]);
        y = fmaf(h[n], Cv[n], y);
      }
      y = fmaf(xv, Dv, y);
      y *= zv / (1.f + __expf(-zv));
      yhp[(size_t)l * D_INNER] = rnd_bf16(y);
      dtv = dtv2; xv = xv2; zv = zv2;
      B0 = B0n; B1 = B1n; B2 = B2n; B3 = B3n;
      C0 = C0n; C1 = C1n; C2 = C2n; C3 = C3n;
    }
  } else {
    for (int l = 0; l < CLEN; l++) {
      const int lp = (l + 1 < CLEN) ? l + 1 : l;
      const float dtv2 = b2f(dtp[(size_t)lp * D_INNER]);
      const float xv2  = b2f(xcp[(size_t)lp * D_INNER]);
      const float zv2  = b2f(zp[(size_t)lp * 2 * D_INNER]);
      const float4 B0n = *(const float4*)(Bp + (size_t)lp * 32 + 0);
      const float4 B1n = *(const float4*)(Bp + (size_t)lp * 32 + 4);
      const float4 B2n = *(const float4*)(Bp + (size_t)lp * 32 + 8);
      const float4 B3n = *(const float4*)(Bp + (size_t)lp * 32 + 12);
      const float4 C0n = *(const float4*)(Bp + (size_t)lp * 32 + 16);
      const float4 C1n = *(const float4*)(Bp + (size_t)lp * 32 + 20);
      const float4 C2n = *(const float4*)(Bp + (size_t)lp * 32 + 24);
      const float4 C3n = *(const float4*)(Bp + (size_t)lp * 32 + 28);
      const float dx = dtv * xv;
      const float Bv[D_STATE] = {B0.x,B0.y,B0.z,B0.w, B1.x,B1.y,B1.z,B1.w,
                                 B2.x,B2.y,B2.z,B2.w, B3.x,B3.y,B3.z,B3.w};
      const float Cv[D_STATE] = {C0.x,C0.y,C0.z,C0.w, C1.x,C1.y,C1.z,C1.w,
                                 C2.x,C2.y,C2.z,C2.w, C3.x,C3.y,C3.z,C3.w};
      float y = 0.f;
      #pragma unroll
      for (int n = 0; n < D_STATE; n++) {
        h[n] = fmaf(__expf(dtv * Ac[n]), h[n], dx * Bv[n]);
        y = fmaf(h[n], Cv[n], y);
      }
      y = fmaf(xv, Dv, y);
      y *= zv / (1.f + __expf(-zv));
      yhp[(size_t)l * D_INNER] = rnd_bf16(y);
      dtv = dtv2; xv = xv2; zv = zv2;
      B0 = B0n; B1 = B1n; B2 = B2n; B3 = B3n;
      C0 = C0n; C1 = C1n; C2 = C2n; C3 = C3n;
    }
  }
}

// ---------------- mean pool over L, two-stage ---------------------------------
__global__ __launch_bounds__(256) void pool1_k(const float* __restrict__ h,
    float* __restrict__ pp) {
  const int d = blockIdx.x * 256 + threadIdx.x;
  const int b = blockIdx.y;
  const int seg = blockIdx.z;
  float s = 0.f;
  const size_t base = (size_t)b * LL + (size_t)seg * 64;
  for (int l = 0; l < 64; l++) s += h[(base + l) * D_MODEL + d];
  pp[((size_t)(b * 16 + seg)) * D_MODEL + d] = s;
}
__global__ __launch_bounds__(256) void pool2_k(const float* __restrict__ pp,
    float* __restrict__ pooled) {
  const int d = blockIdx.x * 256 + threadIdx.x;
  const int b = blockIdx.y;
  float s = 0.f;
  #pragma unroll
  for (int k = 0; k < 16; k++) s += pp[((size_t)(b * 16 + k)) * D_MODEL + d];
  pooled[b * D_MODEL + d] = s * (1.f / LL);
}

// ---------------- classifier head --------------------------------------------
__global__ __launch_bounds__(64) void head_k(const float* __restrict__ pooled,
    const float* __restrict__ hw, const float* __restrict__ hb,
    float* __restrict__ out) {
  const int b = blockIdx.x / N_CLASSES;
  const int j = blockIdx.x % N_CLASSES;
  float s = 0.f;
  for (int k = threadIdx.x; k < D_MODEL; k += 64)
    s = fmaf(pooled[b * D_MODEL + k], hw[j * D_MODEL + k], s);
  #pragma unroll
  for (int o = 32; o; o >>= 1) s += __shfl_down(s, o);
  if (threadIdx.x == 0) out[b * N_CLASSES + j] = s + hb[j];
}

extern "C" void kernel_launch(void* const* d_in, const int* in_sizes, int n_in,
                              void* d_out, int out_size, void* d_ws, size_t ws_size,
                              hipStream_t stream) {
  const float* x0    = (const float*)d_in[0];
  const float* ln1w  = (const float*)d_in[1];
  const float* ln1b  = (const float*)d_in[2];
  const float* inw   = (const float*)d_in[3];
  const float* convw = (const float*)d_in[4];
  const float* convb = (const float*)d_in[5];
  const float* xpw   = (const float*)d_in[6];
  const float* dtpw  = (const float*)d_in[7];
  const float* dtpb  = (const float*)d_in[8];
  const float* Alog  = (const float*)d_in[9];
  const float* Dp    = (const float*)d_in[10];
  const float* outw  = (const float*)d_in[11];
  const float* normw = (const float*)d_in[12];
  const float* normb = (const float*)d_in[13];
  const float* headw = (const float*)d_in[14];
  const float* headb = (const float*)d_in[15];

  float* ws = (float*)d_ws;
  size_t f = 0;
  float* X      = ws + f; f += (size_t)BL * D_MODEL;
  // --- opart overlay region: xzf (8.39M) + xcb (4.19M) + hend (4.19M)
  //     = exactly KSO*BL*D_MODEL = 16.78M floats; all three are dead when
  //     out_proj writes opart (after scan_pass3) and reborn next layer.
  float* xzf    = ws + f; f += (size_t)BL * D_INNER;                 // bf16 xz
  unsigned short* xcb = (unsigned short*)(ws + f);
  f += (size_t)BL * D_INNER / 2;                                     // bf16 xc
  float* hend   = ws + f; f += (size_t)BB * CH * D_INNER * D_STATE;
  float* opart  = xzf;                                               // overlay
  // --- end overlay region
  float* bc     = ws + f; f += (size_t)BL * 32;
  float* dty    = ws + f; f += (size_t)BL * D_INNER;
  float* pooled = ws + f; f += 4096;
  float* pooldp = ws + f; f += (size_t)16 * BB * D_MODEL;
  float* xpart  = ws + f; f += (size_t)KS * BL * 96;
  unsigned short* hh  = (unsigned short*)(ws + f); f += (size_t)BL * D_MODEL / 2;
  unsigned short* yh  = (unsigned short*)(ws + f); f += (size_t)BL * D_INNER / 2;
  unsigned short* dtr = (unsigned short*)(ws + f); f += (size_t)BL * DT_RANK / 2;
  unsigned short* wih = (unsigned short*)(ws + f);
  f += (size_t)N_LAYERS * 2 * D_INNER * D_MODEL / 2;
  unsigned short* woh = (unsigned short*)(ws + f);
  f += (size_t)N_LAYERS * D_MODEL * D_INNER / 2;
  unsigned short* wdt = (unsigned short*)(ws + f);
  f += (size_t)N_LAYERS * D_INNER * DT_RANK / 2;
  unsigned short* xz  = (unsigned short*)xzf;
  unsigned short* dtb = (unsigned short*)dty;
  float* sumdt = xpart;

  round_k<<<(N_LAYERS * 2 * D_INNER * D_MODEL) / 1024, 256, 0, stream>>>(inw, wih);
  round_k<<<(N_LAYERS * D_MODEL * D_INNER) / 1024, 256, 0, stream>>>(outw, woh);
  round_k<<<(N_LAYERS * D_INNER * DT_RANK) / 1024, 256, 0, stream>>>(dtpw, wdt);
  layernorm_bf16_k<<<BL, 256, 0, stream>>>(x0, ln1w, ln1b, hh);

  for (int layer = 0; layer < N_LAYERS; ++layer) {
    const unsigned short* wi = wih + (size_t)layer * 2 * D_INNER * D_MODEL;
    const unsigned short* wo = woh + (size_t)layer * D_MODEL * D_INNER;
    const unsigned short* wd = wdt + (size_t)layer * D_INNER * DT_RANK;
    // xz = h @ in_w^T : 4096x4096x1024, 256² pipeline, bf16 out, XCD remap
    mfma_gemm256_nt<0, 1, 1><<<dim3(16, 16), 512, 0, stream>>>(
        hh, wi, xz, BL, 2 * D_INNER, D_MODEL, 2 * D_INNER);
    conv_silu_k<<<(BL * D_INNER / 4) / 256, 256, 0, stream>>>(
        xz, convw + layer * D_INNER * D_CONV, convb + layer * D_INNER, xcb);
    sgemm_splitk_k<<<dim3(96 / 32, 4096 / 64, KS), 256, 0, stream>>>(
        xcb, xpw + (size_t)layer * 96 * D_INNER, xpart);
    xproj_reduce_k<<<(BL * 96) / 256, 256, 0, stream>>>(xpart, dtr, bc);
    mfma_gemm_nt<2, 1><<<dim3(2048 / 128, 4096 / 128), 256, 0, stream>>>(
        dtr, wd, dtb, BL, D_INNER, DT_RANK, D_INNER, dtpb + layer * D_INNER);
    scan_pass1_k<<<dim3(D_INNER / 256, CH, BB), 256, 0, stream>>>(
        dtb, xcb, bc, Alog + (size_t)layer * D_INNER * D_STATE, hend, sumdt);
    scan_fix_k<<<(BB * D_INNER * D_STATE) / 256, 256, 0, stream>>>(
        hend, sumdt, Alog + (size_t)layer * D_INNER * D_STATE);
    scan_pass3_k<<<dim3(D_INNER / 256, CH, BB), 256, 0, stream>>>(
        dtb, xcb, bc, xz, hend, Alog + (size_t)layer * D_INNER * D_STATE,
        Dp + layer * D_INNER, yh);
    // y @ out_w^T : 4096x1024x2048, 256² pipeline, split-K=4 fp32 partials
    // (opart overlays xz/xcb/hend — all dead here)
    mfma_gemm256_nt<1, KSO, 0><<<dim3(1024 / 256, 4096 / 256, KSO), 512, 0,
                                 stream>>>(
        yh, wo, opart, BL, D_MODEL, D_INNER, D_MODEL);
    const float* Xin = (layer == 0) ? x0 : X;
    if (layer + 1 < N_LAYERS) {
      oreduce_ln_k<0><<<BL, 256, 0, stream>>>(
          opart, Xin, X, ln1w + (layer + 1) * D_MODEL,
          ln1b + (layer + 1) * D_MODEL, hh);
    } else {
      oreduce_ln_k<1><<<BL, 256, 0, stream>>>(opart, Xin, X, normw, normb, dty);
    }
  }

  pool1_k<<<dim3(D_MODEL / 256, BB, 16), 256, 0, stream>>>(dty, pooldp);
  pool2_k<<<dim3(D_MODEL / 256, BB), 256, 0, stream>>>(pooldp, pooled);
  head_k<<<BB * N_CLASSES, 64, 0, stream>>>(pooled, headw, headb, (float*)d_out);
}

// Round 19
// 512.430 us; speedup vs baseline: 1.0009x; 1.0009x over previous
//
#include <hip/hip_runtime.h>
#include <hip/hip_bf16.h>

#define N_LAYERS 2
#define D_MODEL 1024
#define D_INNER 2048
#define D_STATE 16
#define D_CONV 4
#define DT_RANK 64
#define N_CLASSES 10
#define BB 4
#define LL 1024
#define BL (BB*LL)   // 4096 rows
#define CH 32        // scan chunks per sequence
#define CLEN (LL/CH) // 32 steps per chunk
#define KS 8         // split-K segments for x_proj
#define KSO 4        // split-K segments for out_proj (256² pipeline)

typedef __attribute__((ext_vector_type(8))) short bf16x8;
typedef __attribute__((ext_vector_type(8))) unsigned short us8;
typedef __attribute__((ext_vector_type(4))) float f32x4;

typedef const void __attribute__((address_space(1)))* gas_ptr;
typedef void __attribute__((address_space(3)))* las_ptr;
#define GLDS16(g, p) __builtin_amdgcn_global_load_lds((gas_ptr)(g), (las_ptr)(p), 16, 0, 0)

__device__ inline unsigned short rnd_bf16(float x) {
  unsigned u = __float_as_uint(x);
  return (unsigned short)((u + 0x7FFFu + ((u >> 16) & 1u)) >> 16);
}
__device__ inline float b2f(unsigned short u) {
  return __uint_as_float(((unsigned)u) << 16);
}

// round weights to bf16
__global__ __launch_bounds__(256) void round_k(const float* __restrict__ in,
    unsigned short* __restrict__ hi) {
  const int i = blockIdx.x * 256 + threadIdx.x;
  const float4 v = ((const float4*)in)[i];
  ushort4 h4;
  h4.x = rnd_bf16(v.x); h4.y = rnd_bf16(v.y);
  h4.z = rnd_bf16(v.z); h4.w = rnd_bf16(v.w);
  ((ushort4*)hi)[i] = h4;
}

// ---------------- LayerNorm -> bf16 out ---------------------------------------
__global__ __launch_bounds__(256) void layernorm_bf16_k(const float* __restrict__ x,
    const float* __restrict__ w, const float* __restrict__ b,
    unsigned short* __restrict__ oh) {
  const int row = blockIdx.x;
  const int t = threadIdx.x;
  const float4 v = *(const float4*)(x + (size_t)row * D_MODEL + t * 4);
  float s = v.x + v.y + v.z + v.w;
  float q = v.x*v.x + v.y*v.y + v.z*v.z + v.w*v.w;
  #pragma unroll
  for (int o = 32; o; o >>= 1) { s += __shfl_down(s, o); q += __shfl_down(q, o); }
  __shared__ float red[8];
  if ((t & 63) == 0) { red[t >> 6] = s; red[4 + (t >> 6)] = q; }
  __syncthreads();
  s = red[0] + red[1] + red[2] + red[3];
  q = red[4] + red[5] + red[6] + red[7];
  const float mean = s * (1.f / D_MODEL);
  const float var  = q * (1.f / D_MODEL) - mean * mean;
  const float rstd = rsqrtf(var + 1e-5f);
  const float4 wv = *(const float4*)(w + t * 4);
  const float4 bv = *(const float4*)(b + t * 4);
  ushort4 h4;
  h4.x = rnd_bf16((v.x - mean) * rstd * wv.x + bv.x);
  h4.y = rnd_bf16((v.y - mean) * rstd * wv.y + bv.y);
  h4.z = rnd_bf16((v.z - mean) * rstd * wv.z + bv.z);
  h4.w = rnd_bf16((v.w - mean) * rstd * wv.w + bv.w);
  ((ushort4*)(oh + (size_t)row * D_MODEL))[t] = h4;
}

// ---- fused: Xout = Xin + sum(out_proj partials); then LayerNorm -> operand ---
template<int OUT>
__global__ __launch_bounds__(256) void oreduce_ln_k(
    const float* __restrict__ part, const float* __restrict__ Xin,
    float* __restrict__ Xout,
    const float* __restrict__ w, const float* __restrict__ b,
    void* __restrict__ out) {
  const int row = blockIdx.x;
  const int t = threadIdx.x;
  float4 v = *(const float4*)(Xin + (size_t)row * D_MODEL + t * 4);
  #pragma unroll
  for (int k = 0; k < KSO; k++) {
    const float4 p = *(const float4*)(part + (size_t)k * BL * D_MODEL
                                      + (size_t)row * D_MODEL + t * 4);
    v.x += p.x; v.y += p.y; v.z += p.z; v.w += p.w;
  }
  *(float4*)(Xout + (size_t)row * D_MODEL + t * 4) = v;   // residual stream
  float s = v.x + v.y + v.z + v.w;
  float q = v.x*v.x + v.y*v.y + v.z*v.z + v.w*v.w;
  #pragma unroll
  for (int o = 32; o; o >>= 1) { s += __shfl_down(s, o); q += __shfl_down(q, o); }
  __shared__ float red[8];
  if ((t & 63) == 0) { red[t >> 6] = s; red[4 + (t >> 6)] = q; }
  __syncthreads();
  s = red[0] + red[1] + red[2] + red[3];
  q = red[4] + red[5] + red[6] + red[7];
  const float mean = s * (1.f / D_MODEL);
  const float var  = q * (1.f / D_MODEL) - mean * mean;
  const float rstd = rsqrtf(var + 1e-5f);
  const float4 wv = *(const float4*)(w + t * 4);
  const float4 bv = *(const float4*)(b + t * 4);
  float4 o4;
  o4.x = (v.x - mean) * rstd * wv.x + bv.x;
  o4.y = (v.y - mean) * rstd * wv.y + bv.y;
  o4.z = (v.z - mean) * rstd * wv.z + bv.z;
  o4.w = (v.w - mean) * rstd * wv.w + bv.w;
  if constexpr (OUT == 0) {
    ushort4 h4;
    h4.x = rnd_bf16(o4.x); h4.y = rnd_bf16(o4.y);
    h4.z = rnd_bf16(o4.z); h4.w = rnd_bf16(o4.w);
    ((ushort4*)((unsigned short*)out + (size_t)row * D_MODEL))[t] = h4;
  } else {
    *(float4*)((float*)out + (size_t)row * D_MODEL + t * 4) = o4;
  }
}

// ==== 256x256 bf16 MFMA GEMM NT — counted-vmcnt pipeline =====================
// EPI 0: bf16 C. EPI 1: fp32 partials at C + bz*M*ldc (split-K).
// REMAP 1: XCD panel remap (requires grid 16x16). 2 K-tile prefetch, vmcnt(8),
// raw barriers, T2 read swizzle pre-applied to global source. 128 KB LDS.
template<int EPI, int KSEG, int REMAP>
__global__ __launch_bounds__(512) void mfma_gemm256_nt(
    const unsigned short* __restrict__ A, const unsigned short* __restrict__ B,
    void* __restrict__ Cv, int M, int N, int K, int ldc) {
  __shared__ unsigned short S[65536];   // [buf:2][mat:2][256*64] bf16 = 128 KB
  const int tid = threadIdx.x;
  const int l = tid & 63;
  const int w = tid >> 6;
  const int wm = w >> 2, wn = w & 3;
  int bx, by;
  if constexpr (REMAP == 1) {
    const int bid = blockIdx.y * 16 + blockIdx.x;
    const int x = bid & 7, v = bid >> 3;
    bx = (x & 1) * 8 + (v & 7);
    by = (x >> 1) * 4 + (v >> 3);
  } else {
    bx = blockIdx.x; by = blockIdx.y;
  }
  const int m0 = by * 256, n0 = bx * 256;
  const int kseg = K / KSEG;
  const int kbeg = (KSEG > 1) ? blockIdx.z * kseg : 0;
  const int nkt = kseg >> 6;
  const int r8 = (tid >> 3) & 7;
  const int c16s = (tid & 7) ^ r8;                // pre-swizzled source col16

  auto stage1 = [&](int kt, int mat, int half) {
    const unsigned short* base = (mat == 0) ? (A + (size_t)m0 * K)
                                            : (B + (size_t)n0 * K);
    unsigned short* dst = S + ((kt & 1) * 32768 + mat * 16384 + half * 8192);
    #pragma unroll
    for (int e = 0; e < 2; ++e) {
      const int row = half * 128 + e * 64 + (tid >> 3);
      GLDS16(base + (size_t)row * K + kbeg + kt * 64 + c16s * 8,
             dst + e * 4096 + tid * 8);
    }
  };
  auto stage_full = [&](int kt) {
    stage1(kt, 0, 0); stage1(kt, 0, 1); stage1(kt, 1, 0); stage1(kt, 1, 1);
  };

  stage_full(0);
  if (nkt > 1) stage_full(1);

  f32x4 acc[8][4] = {};
  const int fr = l & 15;
  const int fk8 = l >> 4;

  #pragma unroll 1
  for (int kt = 0; kt < nkt; ++kt) {
    if (kt + 1 < nkt) asm volatile("s_waitcnt vmcnt(8)" ::: "memory");
    else              asm volatile("s_waitcnt vmcnt(0)" ::: "memory");
    __builtin_amdgcn_s_barrier();
    __builtin_amdgcn_sched_barrier(0);
    const unsigned short* SA = S + (kt & 1) * 32768;
    const unsigned short* SB = SA + 16384;
    bf16x8 av[8], bv[4];
    // half 0: read + MFMA
    {
      const int c8 = fk8;
      #pragma unroll
      for (int i = 0; i < 8; ++i) {
        const int R = wm * 128 + i * 16 + fr;
        av[i] = *(const bf16x8*)&SA[R * 64 + ((c8 ^ (R & 7)) << 3)];
      }
      #pragma unroll
      for (int j = 0; j < 4; ++j) {
        const int R = wn * 64 + j * 16 + fr;
        bv[j] = *(const bf16x8*)&SB[R * 64 + ((c8 ^ (R & 7)) << 3)];
      }
      __builtin_amdgcn_s_setprio(1);
      #pragma unroll
      for (int i = 0; i < 8; ++i)
        #pragma unroll
        for (int j = 0; j < 4; ++j)
          acc[i][j] = __builtin_amdgcn_mfma_f32_16x16x32_bf16(
              av[i], bv[j], acc[i][j], 0, 0, 0);
      __builtin_amdgcn_s_setprio(0);
    }
    // half 1: read, then free the LDS buffer (barrier) before its MFMA so
    // stage(kt+2) issue overlaps the register-only MFMA burst.
    {
      const int c8 = 4 + fk8;
      #pragma unroll
      for (int i = 0; i < 8; ++i) {
        const int R = wm * 128 + i * 16 + fr;
        av[i] = *(const bf16x8*)&SA[R * 64 + ((c8 ^ (R & 7)) << 3)];
      }
      #pragma unroll
      for (int j = 0; j < 4; ++j) {
        const int R = wn * 64 + j * 16 + fr;
        bv[j] = *(const bf16x8*)&SB[R * 64 + ((c8 ^ (R & 7)) << 3)];
      }
      asm volatile("s_waitcnt lgkmcnt(0)" ::: "memory");
      __builtin_amdgcn_s_barrier();                 // all waves done reading
      __builtin_amdgcn_sched_barrier(0);
      if (kt + 2 < nkt) stage_full(kt + 2);         // overwrite freed buffer
      __builtin_amdgcn_s_setprio(1);
      #pragma unroll
      for (int i = 0; i < 8; ++i)
        #pragma unroll
        for (int j = 0; j < 4; ++j)
          acc[i][j] = __builtin_amdgcn_mfma_f32_16x16x32_bf16(
              av[i], bv[j], acc[i][j], 0, 0, 0);
      __builtin_amdgcn_s_setprio(0);
    }
  }

  const int orow = (l >> 4) * 4, ocol = l & 15;
  if constexpr (EPI == 0) {
    unsigned short* C = (unsigned short*)Cv;
    #pragma unroll
    for (int i = 0; i < 8; ++i)
      #pragma unroll
      for (int j = 0; j < 4; ++j)
        #pragma unroll
        for (int r = 0; r < 4; ++r) {
          const int m = m0 + wm * 128 + i * 16 + orow + r;
          const int n = n0 + wn * 64 + j * 16 + ocol;
          C[(size_t)m * ldc + n] = rnd_bf16(acc[i][j][r]);
        }
  } else {
    float* C = (float*)Cv + (size_t)blockIdx.z * M * ldc;
    #pragma unroll
    for (int i = 0; i < 8; ++i)
      #pragma unroll
      for (int j = 0; j < 4; ++j)
        #pragma unroll
        for (int r = 0; r < 4; ++r) {
          const int m = m0 + wm * 128 + i * 16 + orow + r;
          const int n = n0 + wn * 64 + j * 16 + ocol;
          C[(size_t)m * ldc + n] = acc[i][j][r];
        }
  }
}

// ---- bf16 MFMA GEMM NT 128² (dt GEMM) ----------------------------------------
// EPI 2: softplus+bias -> bf16.
template<int EPI, int KSEG>
__global__ __launch_bounds__(256) void mfma_gemm_nt(
    const unsigned short* __restrict__ Ah, const unsigned short* __restrict__ Bh,
    void* __restrict__ Cv, int M, int N, int K, int ldc,
    const float* __restrict__ bias) {
  __shared__ unsigned short As[128 * 64];
  __shared__ unsigned short Bs[128 * 64];
  const int tid = threadIdx.x;
  const int w = tid >> 6, l = tid & 63;
  const int wr = w >> 1, wc = w & 1;
  const int nbx = gridDim.x;
  const int nwg = nbx * gridDim.y;
  int bid = blockIdx.y * nbx + blockIdx.x;
  bid = (bid & 7) * (nwg >> 3) + (bid >> 3);
  const int st = bid >> 6, wi = bid & 63;
  const int stpr = (nbx >= 8) ? (nbx >> 3) : 1;
  int n0, m0;
  if (nbx >= 8) {
    n0 = ((st % stpr) * 8 + (wi & 7)) * 128;
    m0 = ((st / stpr) * 8 + (wi >> 3)) * 128;
  } else {
    n0 = (bid % nbx) * 128;
    m0 = (bid / nbx) * 128;
  }
  const int kz = (KSEG > 1) ? blockIdx.z : 0;
  const int kbeg = kz * (K / KSEG);
  const int kend = kbeg + K / KSEG;
  const int srow = l >> 3;
  const int scol = (l & 7) * 8;
  const int fr = l & 15;
  const int fk = (l >> 4) * 8;
  f32x4 acc[4][4] = {};

  #pragma unroll 1
  for (int k0 = kbeg; k0 < kend; k0 += 64) {
    __syncthreads();
    #pragma unroll
    for (int it = 0; it < 4; ++it) {
      const int bi = it * 4 + w;
      const int row = bi * 8 + srow;
      GLDS16(Ah + (size_t)(m0 + row) * K + k0 + scol, &As[bi * 512 + l * 8]);
      GLDS16(Bh + (size_t)(n0 + row) * K + k0 + scol, &Bs[bi * 512 + l * 8]);
    }
    __syncthreads();
    #pragma unroll
    for (int kk = 0; kk < 64; kk += 32) {
      bf16x8 a[4], b[4];
      #pragma unroll
      for (int f = 0; f < 4; ++f)
        b[f] = *(const bf16x8*)&Bs[(wc * 64 + f * 16 + fr) * 64 + kk + fk];
      #pragma unroll
      for (int f = 0; f < 4; ++f)
        a[f] = *(const bf16x8*)&As[(wr * 64 + f * 16 + fr) * 64 + kk + fk];
      #pragma unroll
      for (int i = 0; i < 4; ++i)
        #pragma unroll
        for (int j = 0; j < 4; ++j)
          acc[i][j] = __builtin_amdgcn_mfma_f32_16x16x32_bf16(
              a[i], b[j], acc[i][j], 0, 0, 0);
    }
  }
  const int orow = (l >> 4) * 4;
  const int ocol = l & 15;
  if constexpr (EPI == 0 || EPI == 2) {
    unsigned short* Cw = (unsigned short*)Cv;
    #pragma unroll
    for (int i = 0; i < 4; ++i)
      #pragma unroll
      for (int j = 0; j < 4; ++j)
        #pragma unroll
        for (int r = 0; r < 4; ++r) {
          const int m = m0 + wr * 64 + i * 16 + orow + r;
          const int n = n0 + wc * 64 + j * 16 + ocol;
          float vv = acc[i][j][r];
          if constexpr (EPI == 2) {
            vv += bias[n];
            vv = (vv > 20.f) ? vv : log1pf(__expf(vv));
          }
          Cw[(size_t)m * ldc + n] = rnd_bf16(vv);
        }
  } else {
    float* Cw = (float*)Cv + (size_t)kz * M * ldc;
    #pragma unroll
    for (int i = 0; i < 4; ++i)
      #pragma unroll
      for (int j = 0; j < 4; ++j)
        #pragma unroll
        for (int r = 0; r < 4; ++r) {
          const int m = m0 + wr * 64 + i * 16 + orow + r;
          const int n = n0 + wc * 64 + j * 16 + ocol;
          Cw[(size_t)m * ldc + n] = acc[i][j][r];
        }
  }
}

// ---- x_proj split-K (bf16 A) ------------------------------------------------
__global__ __launch_bounds__(256) void sgemm_splitk_k(
    const unsigned short* __restrict__ A, const float* __restrict__ B,
    float* __restrict__ part) {
  __shared__ float As[32][64 + 4];
  __shared__ float Bs[32][32 + 4];
  const int tid = threadIdx.x;
  const int n0 = blockIdx.x * 32;
  const int m0 = blockIdx.y * 64;
  const int kz = blockIdx.z;
  const int tn = (tid & 15) * 2;
  const int tm = (tid >> 4) * 4;
  float acc[4][2] = {};
  for (int kb = 0; kb < 256; kb += 32) {
    const int k0 = kz * 256 + kb;
    {
      int r = tid >> 2, c8 = (tid & 3) * 8;
      us8 u = *(const us8*)(A + (size_t)(m0 + r) * D_INNER + k0 + c8);
      #pragma unroll
      for (int j = 0; j < 8; j++) As[c8 + j][r] = b2f((unsigned short)u[j]);
    }
    {
      int r = tid >> 3, c4 = tid & 7;
      float4 v = *(const float4*)(B + (size_t)(n0 + r) * D_INNER + k0 + c4 * 4);
      Bs[c4*4+0][r] = v.x; Bs[c4*4+1][r] = v.y;
      Bs[c4*4+2][r] = v.z; Bs[c4*4+3][r] = v.w;
    }
    __syncthreads();
    #pragma unroll
    for (int k = 0; k < 32; k++) {
      float a[4], bf[2];
      #pragma unroll
      for (int i = 0; i < 4; i++) a[i] = As[k][tm + i];
      bf[0] = Bs[k][tn]; bf[1] = Bs[k][tn + 1];
      #pragma unroll
      for (int i = 0; i < 4; i++) {
        acc[i][0] = fmaf(a[i], bf[0], acc[i][0]);
        acc[i][1] = fmaf(a[i], bf[1], acc[i][1]);
      }
    }
    __syncthreads();
  }
  float* p = part + (size_t)kz * BL * 96;
  #pragma unroll
  for (int i = 0; i < 4; i++) {
    const int m = m0 + tm + i;
    p[(size_t)m * 96 + n0 + tn]     = acc[i][0];
    p[(size_t)m * 96 + n0 + tn + 1] = acc[i][1];
  }
}

// reduce KS partials; split: cols 0..63 -> bf16 dtr, 64..95 -> fp32 bc[BL][32]
__global__ __launch_bounds__(256) void xproj_reduce_k(
    const float* __restrict__ part, unsigned short* __restrict__ dtr,
    float* __restrict__ bc) {
  const int i = blockIdx.x * 256 + threadIdx.x;   // over BL*96
  const int m = i / 96, col = i % 96;
  float s = 0.f;
  #pragma unroll
  for (int k = 0; k < KS; k++) s += part[(size_t)k * BL * 96 + i];
  if (col < DT_RANK) dtr[(size_t)m * DT_RANK + col] = rnd_bf16(s);
  else               bc[(size_t)m * 32 + (col - DT_RANK)] = s;
}

// ------ causal depthwise conv + SiLU, bf16 in / bf16 out ----------------------
__global__ __launch_bounds__(256) void conv_silu_k(
    const unsigned short* __restrict__ xz,
    const float* __restrict__ cw, const float* __restrict__ cb,
    unsigned short* __restrict__ xc) {
  const int gid = blockIdx.x * 256 + threadIdx.x;
  const int c4 = (gid & (D_INNER / 4 - 1)) << 2;
  const int row = gid >> 9;
  const int l = row & (LL - 1);
  const unsigned short* base = xz + (size_t)row * (2 * D_INNER) + c4;
  const float4 w0 = *(const float4*)(cw + (c4 + 0) * 4);
  const float4 w1 = *(const float4*)(cw + (c4 + 1) * 4);
  const float4 w2 = *(const float4*)(cw + (c4 + 2) * 4);
  const float4 w3 = *(const float4*)(cw + (c4 + 3) * 4);
  float4 acc = *(const float4*)(cb + c4);
  ushort4 uv = *(const ushort4*)base;
  acc.x = fmaf(w0.w, b2f(uv.x), acc.x); acc.y = fmaf(w1.w, b2f(uv.y), acc.y);
  acc.z = fmaf(w2.w, b2f(uv.z), acc.z); acc.w = fmaf(w3.w, b2f(uv.w), acc.w);
  if (l >= 1) {
    uv = *(const ushort4*)(base - 2 * D_INNER);
    acc.x = fmaf(w0.z, b2f(uv.x), acc.x); acc.y = fmaf(w1.z, b2f(uv.y), acc.y);
    acc.z = fmaf(w2.z, b2f(uv.z), acc.z); acc.w = fmaf(w3.z, b2f(uv.w), acc.w);
  }
  if (l >= 2) {
    uv = *(const ushort4*)(base - 4 * D_INNER);
    acc.x = fmaf(w0.y, b2f(uv.x), acc.x); acc.y = fmaf(w1.y, b2f(uv.y), acc.y);
    acc.z = fmaf(w2.y, b2f(uv.z), acc.z); acc.w = fmaf(w3.y, b2f(uv.w), acc.w);
  }
  if (l >= 3) {
    uv = *(const ushort4*)(base - 6 * D_INNER);
    acc.x = fmaf(w0.x, b2f(uv.x), acc.x); acc.y = fmaf(w1.x, b2f(uv.y), acc.y);
    acc.z = fmaf(w2.x, b2f(uv.z), acc.z); acc.w = fmaf(w3.x, b2f(uv.w), acc.w);
  }
  ushort4 o4;
  o4.x = rnd_bf16(acc.x / (1.f + __expf(-acc.x)));
  o4.y = rnd_bf16(acc.y / (1.f + __expf(-acc.y)));
  o4.z = rnd_bf16(acc.z / (1.f + __expf(-acc.z)));
  o4.w = rnd_bf16(acc.w / (1.f + __expf(-acc.w)));
  *(ushort4*)(xc + (size_t)row * D_INNER + c4) = o4;
}

// w-power helper: P[n] = w^(n+1), depth-4 multiply tree
__device__ inline void wpowers(float w1, float* P) {
  const float w2 = w1 * w1, w3 = w2 * w1, w4 = w2 * w2;
  const float w5 = w4 * w1, w6 = w4 * w2, w7 = w4 * w3, w8 = w4 * w4;
  P[0] = w1;  P[1] = w2;  P[2] = w3;  P[3] = w4;
  P[4] = w5;  P[5] = w6;  P[6] = w7;  P[7] = w8;
  P[8]  = w8 * w1;  P[9]  = w8 * w2;  P[10] = w8 * w3;  P[11] = w8 * w4;
  P[12] = w8 * w5;  P[13] = w8 * w6;  P[14] = w8 * w7;  P[15] = w8 * w8;
}

// ------- chunked selective scan, pass 1 (bf16 dt/xc, bc stride 32) ------------
__global__ __launch_bounds__(256) void scan_pass1_k(
    const unsigned short* __restrict__ dt, const unsigned short* __restrict__ xc,
    const float* __restrict__ bc, const float* __restrict__ A_log,
    float* __restrict__ hend, float* __restrict__ sumdt) {
  const int c = blockIdx.x * 256 + threadIdx.x;
  const int k = blockIdx.y;
  const int b = blockIdx.z;
  float Ac[D_STATE];
  bool fast = true;
  #pragma unroll
  for (int n = 0; n < D_STATE; n++) {
    Ac[n] = -__expf(A_log[c * D_STATE + n]);
    fast = fast && (fabsf(Ac[n] + (float)(n + 1)) <= 4e-6f * (float)(n + 1));
  }
  float h[D_STATE] = {};
  float sd = 0.f;
  const size_t r0 = (size_t)b * LL + (size_t)k * CLEN;
  const unsigned short* dtp = dt + r0 * D_INNER + c;
  const unsigned short* xcp = xc + r0 * D_INNER + c;
  const float* Bp  = bc + r0 * 32;

  float dtv = b2f(dtp[0]);
  float xv  = b2f(xcp[0]);
  float4 B0 = *(const float4*)(Bp + 0);
  float4 B1 = *(const float4*)(Bp + 4);
  float4 B2 = *(const float4*)(Bp + 8);
  float4 B3 = *(const float4*)(Bp + 12);
  if (fast) {
    for (int l = 0; l < CLEN; l++) {
      const int lp = (l + 1 < CLEN) ? l + 1 : l;
      const float dtv2 = b2f(dtp[(size_t)lp * D_INNER]);
      const float xv2  = b2f(xcp[(size_t)lp * D_INNER]);
      const float4 B0n = *(const float4*)(Bp + (size_t)lp * 32 + 0);
      const float4 B1n = *(const float4*)(Bp + (size_t)lp * 32 + 4);
      const float4 B2n = *(const float4*)(Bp + (size_t)lp * 32 + 8);
      const float4 B3n = *(const float4*)(Bp + (size_t)lp * 32 + 12);
      sd += dtv;
      const float dx = dtv * xv;
      float P[D_STATE];
      wpowers(__expf(-dtv), P);
      const float Bv[D_STATE] = {B0.x,B0.y,B0.z,B0.w, B1.x,B1.y,B1.z,B1.w,
                                 B2.x,B2.y,B2.z,B2.w, B3.x,B3.y,B3.z,B3.w};
      #pragma unroll
      for (int n = 0; n < D_STATE; n++)
        h[n] = fmaf(P[n], h[n], dx * Bv[n]);
      dtv = dtv2; xv = xv2; B0 = B0n; B1 = B1n; B2 = B2n; B3 = B3n;
    }
  } else {
    for (int l = 0; l < CLEN; l++) {
      const int lp = (l + 1 < CLEN) ? l + 1 : l;
      const float dtv2 = b2f(dtp[(size_t)lp * D_INNER]);
      const float xv2  = b2f(xcp[(size_t)lp * D_INNER]);
      const float4 B0n = *(const float4*)(Bp + (size_t)lp * 32 + 0);
      const float4 B1n = *(const float4*)(Bp + (size_t)lp * 32 + 4);
      const float4 B2n = *(const float4*)(Bp + (size_t)lp * 32 + 8);
      const float4 B3n = *(const float4*)(Bp + (size_t)lp * 32 + 12);
      sd += dtv;
      const float dx = dtv * xv;
      const float Bv[D_STATE] = {B0.x,B0.y,B0.z,B0.w, B1.x,B1.y,B1.z,B1.w,
                                 B2.x,B2.y,B2.z,B2.w, B3.x,B3.y,B3.z,B3.w};
      #pragma unroll
      for (int n = 0; n < D_STATE; n++)
        h[n] = fmaf(__expf(dtv * Ac[n]), h[n], dx * Bv[n]);
      dtv = dtv2; xv = xv2; B0 = B0n; B1 = B1n; B2 = B2n; B3 = B3n;
    }
  }
  float* he = hend + (((size_t)(b * CH + k) * D_INNER + c) << 4);
  #pragma unroll
  for (int n = 0; n < D_STATE; n += 4)
    *(float4*)(he + n) = make_float4(h[n], h[n+1], h[n+2], h[n+3]);
  sumdt[(size_t)(b * CH + k) * D_INNER + c] = sd;
}

// ------- chunked scan fixup ---------------------------------------------------
__global__ __launch_bounds__(256) void scan_fix_k(
    float* __restrict__ hend, const float* __restrict__ sumdt,
    const float* __restrict__ A_log) {
  const int gid = blockIdx.x * 256 + threadIdx.x;
  const int n = gid & 15;
  const int c = (gid >> 4) & (D_INNER - 1);
  const int b = gid >> 15;
  const float Ac = -__expf(A_log[c * D_STATE + n]);
  float hrun = 0.f;
  for (int k = 0; k < CH; k++) {
    const size_t base = (size_t)(b * CH + k) * D_INNER + c;
    const float sd = sumdt[base];
    float* hp = hend + (base << 4) + n;
    const float tmp = *hp;
    *hp = hrun;
    hrun = fmaf(__expf(Ac * sd), hrun, tmp);
  }
}

// ------- chunked scan pass 3 (bc stride 32, fast w-power path) -----------------
__global__ __launch_bounds__(256) void scan_pass3_k(
    const unsigned short* __restrict__ dt, const unsigned short* __restrict__ xc,
    const float* __restrict__ bc, const unsigned short* __restrict__ xz,
    const float* __restrict__ h0, const float* __restrict__ A_log,
    const float* __restrict__ Dp, unsigned short* __restrict__ yh) {
  const int c = blockIdx.x * 256 + threadIdx.x;
  const int k = blockIdx.y;
  const int b = blockIdx.z;
  float Ac[D_STATE];
  bool fast = true;
  #pragma unroll
  for (int n = 0; n < D_STATE; n++) {
    Ac[n] = -__expf(A_log[c * D_STATE + n]);
    fast = fast && (fabsf(Ac[n] + (float)(n + 1)) <= 4e-6f * (float)(n + 1));
  }
  const float Dv = Dp[c];
  float h[D_STATE];
  const float* hp = h0 + (((size_t)(b * CH + k) * D_INNER + c) << 4);
  #pragma unroll
  for (int n = 0; n < D_STATE; n += 4) {
    const float4 v = *(const float4*)(hp + n);
    h[n] = v.x; h[n+1] = v.y; h[n+2] = v.z; h[n+3] = v.w;
  }
  const size_t r0 = (size_t)b * LL + (size_t)k * CLEN;
  const unsigned short* dtp = dt + r0 * D_INNER + c;
  const unsigned short* xcp = xc + r0 * D_INNER + c;
  const float* Bp  = bc + r0 * 32;
  const unsigned short* zp = xz + r0 * (size_t)(2 * D_INNER) + D_INNER + c;
  unsigned short* yhp = yh + r0 * D_INNER + c;

  float dtv = b2f(dtp[0]);
  float xv  = b2f(xcp[0]);
  float zv  = b2f(zp[0]);
  float4 B0 = *(const float4*)(Bp + 0);
  float4 B1 = *(const float4*)(Bp + 4);
  float4 B2 = *(const float4*)(Bp + 8);
  float4 B3 = *(const float4*)(Bp + 12);
  float4 C0 = *(const float4*)(Bp + 16);
  float4 C1 = *(const float4*)(Bp + 20);
  float4 C2 = *(const float4*)(Bp + 24);
  float4 C3 = *(const float4*)(Bp + 28);
  if (fast) {
    for (int l = 0; l < CLEN; l++) {
      const int lp = (l + 1 < CLEN) ? l + 1 : l;
      const float dtv2 = b2f(dtp[(size_t)lp * D_INNER]);
      const float xv2  = b2f(xcp[(size_t)lp * D_INNER]);
      const float zv2  = b2f(zp[(size_t)lp * 2 * D_INNER]);
      const float4 B0n = *(const float4*)(Bp + (size_t)lp * 32 + 0);
      const float4 B1n = *(const float4*)(Bp + (size_t)lp * 32 + 4);
      const float4 B2n = *(const float4*)(Bp + (size_t)lp * 32 + 8);
      const float4 B3n = *(const float4*)(Bp + (size_t)lp * 32 + 12);
      const float4 C0n = *(const float4*)(Bp + (size_t)lp * 32 + 16);
      const float4 C1n = *(const float4*)(Bp + (size_t)lp * 32 + 20);
      const float4 C2n = *(const float4*)(Bp + (size_t)lp * 32 + 24);
      const float4 C3n = *(const float4*)(Bp + (size_t)lp * 32 + 28);
      const float dx = dtv * xv;
      float P[D_STATE];
      wpowers(__expf(-dtv), P);
      const float Bv[D_STATE] = {B0.x,B0.y,B0.z,B0.w, B1.x,B1.y,B1.z,B1.w,
                                 B2.x,B2.y,B2.z,B2.w, B3.x,B3.y,B3.z,B3.w};
      const float Cv[D_STATE] = {C0.x,C0.y,C0.z,C0.w, C1.x,C1.y,C1.z,C1.w,
                                 C2.x,C2.y,C2.z,C2.w, C3.x,C3.y,C3.z,C3.w};
      float y = 0.f;
      #pragma unroll
      for (int n = 0; n < D_STATE; n++) {
        h[n] = fmaf(P[n], h[n], dx * Bv[n]);
        y = fmaf(h[n], Cv[n], y);
      }
      y = fmaf(xv, Dv, y);
      y *= zv / (1.f + __expf(-zv));
      yhp[(size_t)l * D_INNER] = rnd_bf16(y);
      dtv = dtv2; xv = xv2; zv = zv2;
      B0 = B0n; B1 = B1n; B2 = B2n; B3 = B3n;
      C0 = C0n; C1 = C1n; C2 = C2n; C3 = C3n;
    }
  } else {
    for (int l = 0; l < CLEN; l++) {
      const int lp = (l + 1 < CLEN) ? l + 1 : l;
      const float dtv2 = b2f(dtp[(size_t)lp * D_INNER]);
      const float xv2  = b2f(xcp[(size_t)lp * D_INNER]);
      const float zv2  = b2f(zp[(size_t)lp * 2 * D_INNER]);
      const float4 B0n = *(const float4*)(Bp + (size_t)lp * 32 + 0);
      const float4 B1n = *(const float4*)(Bp + (size_t)lp * 32 + 4);
      const float4 B2n = *(const float4*)(Bp + (size_t)lp * 32 + 8);
      const float4 B3n = *(const float4*)(Bp + (size_t)lp * 32 + 12);
      const float4 C0n = *(const float4*)(Bp + (size_t)lp * 32 + 16);
      const float4 C1n = *(const float4*)(Bp + (size_t)lp * 32 + 20);
      const float4 C2n = *(const float4*)(Bp + (size_t)lp * 32 + 24);
      const float4 C3n = *(const float4*)(Bp + (size_t)lp * 32 + 28);
      const float dx = dtv * xv;
      const float Bv[D_STATE] = {B0.x,B0.y,B0.z,B0.w, B1.x,B1.y,B1.z,B1.w,
                                 B2.x,B2.y,B2.z,B2.w, B3.x,B3.y,B3.z,B3.w};
      const float Cv[D_STATE] = {C0.x,C0.y,C0.z,C0.w, C1.x,C1.y,C1.z,C1.w,
                                 C2.x,C2.y,C2.z,C2.w, C3.x,C3.y,C3.z,C3.w};
      float y = 0.f;
      #pragma unroll
      for (int n = 0; n < D_STATE; n++) {
        h[n] = fmaf(__expf(dtv * Ac[n]), h[n], dx * Bv[n]);
        y = fmaf(h[n], Cv[n], y);
      }
      y = fmaf(xv, Dv, y);
      y *= zv / (1.f + __expf(-zv));
      yhp[(size_t)l * D_INNER] = rnd_bf16(y);
      dtv = dtv2; xv = xv2; zv = zv2;
      B0 = B0n; B1 = B1n; B2 = B2n; B3 = B3n;
      C0 = C0n; C1 = C1n; C2 = C2n; C3 = C3n;
    }
  }
}

// ---------------- mean pool over L, two-stage ---------------------------------
__global__ __launch_bounds__(256) void pool1_k(const float* __restrict__ h,
    float* __restrict__ pp) {
  const int d = blockIdx.x * 256 + threadIdx.x;
  const int b = blockIdx.y;
  const int seg = blockIdx.z;
  float s = 0.f;
  const size_t base = (size_t)b * LL + (size_t)seg * 64;
  for (int l = 0; l < 64; l++) s += h[(base + l) * D_MODEL + d];
  pp[((size_t)(b * 16 + seg)) * D_MODEL + d] = s;
}
__global__ __launch_bounds__(256) void pool2_k(const float* __restrict__ pp,
    float* __restrict__ pooled) {
  const int d = blockIdx.x * 256 + threadIdx.x;
  const int b = blockIdx.y;
  float s = 0.f;
  #pragma unroll
  for (int k = 0; k < 16; k++) s += pp[((size_t)(b * 16 + k)) * D_MODEL + d];
  pooled[b * D_MODEL + d] = s * (1.f / LL);
}

// ---------------- classifier head --------------------------------------------
__global__ __launch_bounds__(64) void head_k(const float* __restrict__ pooled,
    const float* __restrict__ hw, const float* __restrict__ hb,
    float* __restrict__ out) {
  const int b = blockIdx.x / N_CLASSES;
  const int j = blockIdx.x % N_CLASSES;
  float s = 0.f;
  for (int k = threadIdx.x; k < D_MODEL; k += 64)
    s = fmaf(pooled[b * D_MODEL + k], hw[j * D_MODEL + k], s);
  #pragma unroll
  for (int o = 32; o; o >>= 1) s += __shfl_down(s, o);
  if (threadIdx.x == 0) out[b * N_CLASSES + j] = s + hb[j];
}

extern "C" void kernel_launch(void* const* d_in, const int* in_sizes, int n_in,
                              void* d_out, int out_size, void* d_ws, size_t ws_size,
                              hipStream_t stream) {
  const float* x0    = (const float*)d_in[0];
  const float* ln1w  = (const float*)d_in[1];
  const float* ln1b  = (const float*)d_in[2];
  const float* inw   = (const float*)d_in[3];
  const float* convw = (const float*)d_in[4];
  const float* convb = (const float*)d_in[5];
  const float* xpw   = (const float*)d_in[6];
  const float* dtpw  = (const float*)d_in[7];
  const float* dtpb  = (const float*)d_in[8];
  const float* Alog  = (const float*)d_in[9];
  const float* Dp    = (const float*)d_in[10];
  const float* outw  = (const float*)d_in[11];
  const float* normw = (const float*)d_in[12];
  const float* normb = (const float*)d_in[13];
  const float* headw = (const float*)d_in[14];
  const float* headb = (const float*)d_in[15];

  float* ws = (float*)d_ws;
  size_t f = 0;
  float* X      = ws + f; f += (size_t)BL * D_MODEL;
  // --- opart overlay region: xzf (8.39M) + xcb (4.19M) + hend (4.19M)
  //     = exactly KSO*BL*D_MODEL = 16.78M floats; all three are dead when
  //     out_proj writes opart (after scan_pass3) and reborn next layer.
  float* xzf    = ws + f; f += (size_t)BL * D_INNER;                 // bf16 xz
  unsigned short* xcb = (unsigned short*)(ws + f);
  f += (size_t)BL * D_INNER / 2;                                     // bf16 xc
  float* hend   = ws + f; f += (size_t)BB * CH * D_INNER * D_STATE;
  float* opart  = xzf;                                               // overlay
  // --- end overlay region
  float* bc     = ws + f; f += (size_t)BL * 32;
  float* dty    = ws + f; f += (size_t)BL * D_INNER;
  float* pooled = ws + f; f += 4096;
  float* pooldp = ws + f; f += (size_t)16 * BB * D_MODEL;
  float* xpart  = ws + f; f += (size_t)KS * BL * 96;
  unsigned short* hh  = (unsigned short*)(ws + f); f += (size_t)BL * D_MODEL / 2;
  unsigned short* yh  = (unsigned short*)(ws + f); f += (size_t)BL * D_INNER / 2;
  unsigned short* dtr = (unsigned short*)(ws + f); f += (size_t)BL * DT_RANK / 2;
  unsigned short* wih = (unsigned short*)(ws + f);
  f += (size_t)N_LAYERS * 2 * D_INNER * D_MODEL / 2;
  unsigned short* woh = (unsigned short*)(ws + f);
  f += (size_t)N_LAYERS * D_MODEL * D_INNER / 2;
  unsigned short* wdt = (unsigned short*)(ws + f);
  f += (size_t)N_LAYERS * D_INNER * DT_RANK / 2;
  unsigned short* xz  = (unsigned short*)xzf;
  unsigned short* dtb = (unsigned short*)dty;
  float* sumdt = xpart;

  round_k<<<(N_LAYERS * 2 * D_INNER * D_MODEL) / 1024, 256, 0, stream>>>(inw, wih);
  round_k<<<(N_LAYERS * D_MODEL * D_INNER) / 1024, 256, 0, stream>>>(outw, woh);
  round_k<<<(N_LAYERS * D_INNER * DT_RANK) / 1024, 256, 0, stream>>>(dtpw, wdt);
  layernorm_bf16_k<<<BL, 256, 0, stream>>>(x0, ln1w, ln1b, hh);

  for (int layer = 0; layer < N_LAYERS; ++layer) {
    const unsigned short* wi = wih + (size_t)layer * 2 * D_INNER * D_MODEL;
    const unsigned short* wo = woh + (size_t)layer * D_MODEL * D_INNER;
    const unsigned short* wd = wdt + (size_t)layer * D_INNER * DT_RANK;
    // xz = h @ in_w^T : 4096x4096x1024, 256² pipeline, bf16 out, XCD remap
    mfma_gemm256_nt<0, 1, 1><<<dim3(16, 16), 512, 0, stream>>>(
        hh, wi, xz, BL, 2 * D_INNER, D_MODEL, 2 * D_INNER);
    conv_silu_k<<<(BL * D_INNER / 4) / 256, 256, 0, stream>>>(
        xz, convw + layer * D_INNER * D_CONV, convb + layer * D_INNER, xcb);
    sgemm_splitk_k<<<dim3(96 / 32, 4096 / 64, KS), 256, 0, stream>>>(
        xcb, xpw + (size_t)layer * 96 * D_INNER, xpart);
    xproj_reduce_k<<<(BL * 96) / 256, 256, 0, stream>>>(xpart, dtr, bc);
    mfma_gemm_nt<2, 1><<<dim3(2048 / 128, 4096 / 128), 256, 0, stream>>>(
        dtr, wd, dtb, BL, D_INNER, DT_RANK, D_INNER, dtpb + layer * D_INNER);
    scan_pass1_k<<<dim3(D_INNER / 256, CH, BB), 256, 0, stream>>>(
        dtb, xcb, bc, Alog + (size_t)layer * D_INNER * D_STATE, hend, sumdt);
    scan_fix_k<<<(BB * D_INNER * D_STATE) / 256, 256, 0, stream>>>(
        hend, sumdt, Alog + (size_t)layer * D_INNER * D_STATE);
    scan_pass3_k<<<dim3(D_INNER / 256, CH, BB), 256, 0, stream>>>(
        dtb, xcb, bc, xz, hend, Alog + (size_t)layer * D_INNER * D_STATE,
        Dp + layer * D_INNER, yh);
    // y @ out_w^T : 4096x1024x2048, 256² pipeline, split-K=4 fp32 partials
    // (opart overlays xz/xcb/hend — all dead here)
    mfma_gemm256_nt<1, KSO, 0><<<dim3(1024 / 256, 4096 / 256, KSO), 512, 0,
                                 stream>>>(
        yh, wo, opart, BL, D_MODEL, D_INNER, D_MODEL);
    const float* Xin = (layer == 0) ? x0 : X;
    if (layer + 1 < N_LAYERS) {
      oreduce_ln_k<0><<<BL, 256, 0, stream>>>(
          opart, Xin, X, ln1w + (layer + 1) * D_MODEL,
          ln1b + (layer + 1) * D_MODEL, hh);
    } else {
      oreduce_ln_k<1><<<BL, 256, 0, stream>>>(opart, Xin, X, normw, normb, dty);
    }
  }

  pool1_k<<<dim3(D_MODEL / 256, BB, 16), 256, 0, stream>>>(dty, pooldp);
  pool2_k<<<dim3(D_MODEL / 256, BB), 256, 0, stream>>>(pooldp, pooled);
  head_k<<<BB * N_CLASSES, 64, 0, stream>>>(pooled, headw, headb, (float*)d_out);
}

// Round 20
// 511.596 us; speedup vs baseline: 1.0026x; 1.0016x over previous
//
#include <hip/hip_runtime.h>
#include <hip/hip_bf16.h>

#define N_LAYERS 2
#define D_MODEL 1024
#define D_INNER 2048
#define D_STATE 16
#define D_CONV 4
#define DT_RANK 64
#define N_CLASSES 10
#define BB 4
#define LL 1024
#define BL (BB*LL)   // 4096 rows
#define CH 32        // scan chunks per sequence
#define CLEN (LL/CH) // 32 steps per chunk
#define KS 8         // split-K segments for x_proj
#define KSO 4        // split-K segments for out_proj (256² pipeline)

typedef __attribute__((ext_vector_type(8))) short bf16x8;
typedef __attribute__((ext_vector_type(8))) unsigned short us8;
typedef __attribute__((ext_vector_type(4))) float f32x4;

typedef const void __attribute__((address_space(1)))* gas_ptr;
typedef void __attribute__((address_space(3)))* las_ptr;
#define GLDS16(g, p) __builtin_amdgcn_global_load_lds((gas_ptr)(g), (las_ptr)(p), 16, 0, 0)

__device__ inline unsigned short rnd_bf16(float x) {
  unsigned u = __float_as_uint(x);
  return (unsigned short)((u + 0x7FFFu + ((u >> 16) & 1u)) >> 16);
}
__device__ inline float b2f(unsigned short u) {
  return __uint_as_float(((unsigned)u) << 16);
}

// round weights to bf16
__global__ __launch_bounds__(256) void round_k(const float* __restrict__ in,
    unsigned short* __restrict__ hi) {
  const int i = blockIdx.x * 256 + threadIdx.x;
  const float4 v = ((const float4*)in)[i];
  ushort4 h4;
  h4.x = rnd_bf16(v.x); h4.y = rnd_bf16(v.y);
  h4.z = rnd_bf16(v.z); h4.w = rnd_bf16(v.w);
  ((ushort4*)hi)[i] = h4;
}

// ---------------- LayerNorm -> bf16 out ---------------------------------------
__global__ __launch_bounds__(256) void layernorm_bf16_k(const float* __restrict__ x,
    const float* __restrict__ w, const float* __restrict__ b,
    unsigned short* __restrict__ oh) {
  const int row = blockIdx.x;
  const int t = threadIdx.x;
  const float4 v = *(const float4*)(x + (size_t)row * D_MODEL + t * 4);
  float s = v.x + v.y + v.z + v.w;
  float q = v.x*v.x + v.y*v.y + v.z*v.z + v.w*v.w;
  #pragma unroll
  for (int o = 32; o; o >>= 1) { s += __shfl_down(s, o); q += __shfl_down(q, o); }
  __shared__ float red[8];
  if ((t & 63) == 0) { red[t >> 6] = s; red[4 + (t >> 6)] = q; }
  __syncthreads();
  s = red[0] + red[1] + red[2] + red[3];
  q = red[4] + red[5] + red[6] + red[7];
  const float mean = s * (1.f / D_MODEL);
  const float var  = q * (1.f / D_MODEL) - mean * mean;
  const float rstd = rsqrtf(var + 1e-5f);
  const float4 wv = *(const float4*)(w + t * 4);
  const float4 bv = *(const float4*)(b + t * 4);
  ushort4 h4;
  h4.x = rnd_bf16((v.x - mean) * rstd * wv.x + bv.x);
  h4.y = rnd_bf16((v.y - mean) * rstd * wv.y + bv.y);
  h4.z = rnd_bf16((v.z - mean) * rstd * wv.z + bv.z);
  h4.w = rnd_bf16((v.w - mean) * rstd * wv.w + bv.w);
  ((ushort4*)(oh + (size_t)row * D_MODEL))[t] = h4;
}

// ---- fused: Xout = Xin + sum(out_proj partials); then LayerNorm -> operand ---
template<int OUT>
__global__ __launch_bounds__(256) void oreduce_ln_k(
    const float* __restrict__ part, const float* __restrict__ Xin,
    float* __restrict__ Xout,
    const float* __restrict__ w, const float* __restrict__ b,
    void* __restrict__ out) {
  const int row = blockIdx.x;
  const int t = threadIdx.x;
  float4 v = *(const float4*)(Xin + (size_t)row * D_MODEL + t * 4);
  #pragma unroll
  for (int k = 0; k < KSO; k++) {
    const float4 p = *(const float4*)(part + (size_t)k * BL * D_MODEL
                                      + (size_t)row * D_MODEL + t * 4);
    v.x += p.x; v.y += p.y; v.z += p.z; v.w += p.w;
  }
  *(float4*)(Xout + (size_t)row * D_MODEL + t * 4) = v;   // residual stream
  float s = v.x + v.y + v.z + v.w;
  float q = v.x*v.x + v.y*v.y + v.z*v.z + v.w*v.w;
  #pragma unroll
  for (int o = 32; o; o >>= 1) { s += __shfl_down(s, o); q += __shfl_down(q, o); }
  __shared__ float red[8];
  if ((t & 63) == 0) { red[t >> 6] = s; red[4 + (t >> 6)] = q; }
  __syncthreads();
  s = red[0] + red[1] + red[2] + red[3];
  q = red[4] + red[5] + red[6] + red[7];
  const float mean = s * (1.f / D_MODEL);
  const float var  = q * (1.f / D_MODEL) - mean * mean;
  const float rstd = rsqrtf(var + 1e-5f);
  const float4 wv = *(const float4*)(w + t * 4);
  const float4 bv = *(const float4*)(b + t * 4);
  float4 o4;
  o4.x = (v.x - mean) * rstd * wv.x + bv.x;
  o4.y = (v.y - mean) * rstd * wv.y + bv.y;
  o4.z = (v.z - mean) * rstd * wv.z + bv.z;
  o4.w = (v.w - mean) * rstd * wv.w + bv.w;
  if constexpr (OUT == 0) {
    ushort4 h4;
    h4.x = rnd_bf16(o4.x); h4.y = rnd_bf16(o4.y);
    h4.z = rnd_bf16(o4.z); h4.w = rnd_bf16(o4.w);
    ((ushort4*)((unsigned short*)out + (size_t)row * D_MODEL))[t] = h4;
  } else {
    *(float4*)((float*)out + (size_t)row * D_MODEL + t * 4) = o4;
  }
}

// ==== 256x256 bf16 MFMA GEMM NT — counted-vmcnt pipeline =====================
// EPI 0: bf16 C. EPI 1: fp32 partials at C + bz*M*ldc (split-K).
// REMAP 1: XCD panel remap (requires grid 16x16). 2 K-tile prefetch, vmcnt(8),
// raw barriers, T2 read swizzle pre-applied to global source. 128 KB LDS.
template<int EPI, int KSEG, int REMAP>
__global__ __launch_bounds__(512) void mfma_gemm256_nt(
    const unsigned short* __restrict__ A, const unsigned short* __restrict__ B,
    void* __restrict__ Cv, int M, int N, int K, int ldc) {
  __shared__ unsigned short S[65536];   // [buf:2][mat:2][256*64] bf16 = 128 KB
  const int tid = threadIdx.x;
  const int l = tid & 63;
  const int w = tid >> 6;
  const int wm = w >> 2, wn = w & 3;
  int bx, by;
  if constexpr (REMAP == 1) {
    const int bid = blockIdx.y * 16 + blockIdx.x;
    const int x = bid & 7, v = bid >> 3;
    bx = (x & 1) * 8 + (v & 7);
    by = (x >> 1) * 4 + (v >> 3);
  } else {
    bx = blockIdx.x; by = blockIdx.y;
  }
  const int m0 = by * 256, n0 = bx * 256;
  const int kseg = K / KSEG;
  const int kbeg = (KSEG > 1) ? blockIdx.z * kseg : 0;
  const int nkt = kseg >> 6;
  const int r8 = (tid >> 3) & 7;
  const int c16s = (tid & 7) ^ r8;                // pre-swizzled source col16

  auto stage1 = [&](int kt, int mat, int half) {
    const unsigned short* base = (mat == 0) ? (A + (size_t)m0 * K)
                                            : (B + (size_t)n0 * K);
    unsigned short* dst = S + ((kt & 1) * 32768 + mat * 16384 + half * 8192);
    #pragma unroll
    for (int e = 0; e < 2; ++e) {
      const int row = half * 128 + e * 64 + (tid >> 3);
      GLDS16(base + (size_t)row * K + kbeg + kt * 64 + c16s * 8,
             dst + e * 4096 + tid * 8);
    }
  };
  auto stage_full = [&](int kt) {
    stage1(kt, 0, 0); stage1(kt, 0, 1); stage1(kt, 1, 0); stage1(kt, 1, 1);
  };

  stage_full(0);
  if (nkt > 1) stage_full(1);

  f32x4 acc[8][4] = {};
  const int fr = l & 15;
  const int fk8 = l >> 4;

  #pragma unroll 1
  for (int kt = 0; kt < nkt; ++kt) {
    if (kt + 1 < nkt) asm volatile("s_waitcnt vmcnt(8)" ::: "memory");
    else              asm volatile("s_waitcnt vmcnt(0)" ::: "memory");
    __builtin_amdgcn_s_barrier();
    __builtin_amdgcn_sched_barrier(0);
    const unsigned short* SA = S + (kt & 1) * 32768;
    const unsigned short* SB = SA + 16384;
    bf16x8 av[8], bv[4];
    // half 0: read + MFMA
    {
      const int c8 = fk8;
      #pragma unroll
      for (int i = 0; i < 8; ++i) {
        const int R = wm * 128 + i * 16 + fr;
        av[i] = *(const bf16x8*)&SA[R * 64 + ((c8 ^ (R & 7)) << 3)];
      }
      #pragma unroll
      for (int j = 0; j < 4; ++j) {
        const int R = wn * 64 + j * 16 + fr;
        bv[j] = *(const bf16x8*)&SB[R * 64 + ((c8 ^ (R & 7)) << 3)];
      }
      __builtin_amdgcn_s_setprio(1);
      #pragma unroll
      for (int i = 0; i < 8; ++i)
        #pragma unroll
        for (int j = 0; j < 4; ++j)
          acc[i][j] = __builtin_amdgcn_mfma_f32_16x16x32_bf16(
              av[i], bv[j], acc[i][j], 0, 0, 0);
      __builtin_amdgcn_s_setprio(0);
    }
    // half 1: read, then free the LDS buffer (barrier) before its MFMA so
    // stage(kt+2) issue overlaps the register-only MFMA burst.
    {
      const int c8 = 4 + fk8;
      #pragma unroll
      for (int i = 0; i < 8; ++i) {
        const int R = wm * 128 + i * 16 + fr;
        av[i] = *(const bf16x8*)&SA[R * 64 + ((c8 ^ (R & 7)) << 3)];
      }
      #pragma unroll
      for (int j = 0; j < 4; ++j) {
        const int R = wn * 64 + j * 16 + fr;
        bv[j] = *(const bf16x8*)&SB[R * 64 + ((c8 ^ (R & 7)) << 3)];
      }
      asm volatile("s_waitcnt lgkmcnt(0)" ::: "memory");
      __builtin_amdgcn_s_barrier();                 // all waves done reading
      __builtin_amdgcn_sched_barrier(0);
      if (kt + 2 < nkt) stage_full(kt + 2);         // overwrite freed buffer
      __builtin_amdgcn_s_setprio(1);
      #pragma unroll
      for (int i = 0; i < 8; ++i)
        #pragma unroll
        for (int j = 0; j < 4; ++j)
          acc[i][j] = __builtin_amdgcn_mfma_f32_16x16x32_bf16(
              av[i], bv[j], acc[i][j], 0, 0, 0);
      __builtin_amdgcn_s_setprio(0);
    }
  }

  const int orow = (l >> 4) * 4, ocol = l & 15;
  if constexpr (EPI == 0) {
    unsigned short* C = (unsigned short*)Cv;
    #pragma unroll
    for (int i = 0; i < 8; ++i)
      #pragma unroll
      for (int j = 0; j < 4; ++j)
        #pragma unroll
        for (int r = 0; r < 4; ++r) {
          const int m = m0 + wm * 128 + i * 16 + orow + r;
          const int n = n0 + wn * 64 + j * 16 + ocol;
          C[(size_t)m * ldc + n] = rnd_bf16(acc[i][j][r]);
        }
  } else {
    float* C = (float*)Cv + (size_t)blockIdx.z * M * ldc;
    #pragma unroll
    for (int i = 0; i < 8; ++i)
      #pragma unroll
      for (int j = 0; j < 4; ++j)
        #pragma unroll
        for (int r = 0; r < 4; ++r) {
          const int m = m0 + wm * 128 + i * 16 + orow + r;
          const int n = n0 + wn * 64 + j * 16 + ocol;
          C[(size_t)m * ldc + n] = acc[i][j][r];
        }
  }
}

// ---- bf16 MFMA GEMM NT 128² (dt GEMM) ----------------------------------------
// EPI 2: softplus+bias -> bf16.
template<int EPI, int KSEG>
__global__ __launch_bounds__(256) void mfma_gemm_nt(
    const unsigned short* __restrict__ Ah, const unsigned short* __restrict__ Bh,
    void* __restrict__ Cv, int M, int N, int K, int ldc,
    const float* __restrict__ bias) {
  __shared__ unsigned short As[128 * 64];
  __shared__ unsigned short Bs[128 * 64];
  const int tid = threadIdx.x;
  const int w = tid >> 6, l = tid & 63;
  const int wr = w >> 1, wc = w & 1;
  const int nbx = gridDim.x;
  const int nwg = nbx * gridDim.y;
  int bid = blockIdx.y * nbx + blockIdx.x;
  bid = (bid & 7) * (nwg >> 3) + (bid >> 3);
  const int st = bid >> 6, wi = bid & 63;
  const int stpr = (nbx >= 8) ? (nbx >> 3) : 1;
  int n0, m0;
  if (nbx >= 8) {
    n0 = ((st % stpr) * 8 + (wi & 7)) * 128;
    m0 = ((st / stpr) * 8 + (wi >> 3)) * 128;
  } else {
    n0 = (bid % nbx) * 128;
    m0 = (bid / nbx) * 128;
  }
  const int kz = (KSEG > 1) ? blockIdx.z : 0;
  const int kbeg = kz * (K / KSEG);
  const int kend = kbeg + K / KSEG;
  const int srow = l >> 3;
  const int scol = (l & 7) * 8;
  const int fr = l & 15;
  const int fk = (l >> 4) * 8;
  f32x4 acc[4][4] = {};

  #pragma unroll 1
  for (int k0 = kbeg; k0 < kend; k0 += 64) {
    __syncthreads();
    #pragma unroll
    for (int it = 0; it < 4; ++it) {
      const int bi = it * 4 + w;
      const int row = bi * 8 + srow;
      GLDS16(Ah + (size_t)(m0 + row) * K + k0 + scol, &As[bi * 512 + l * 8]);
      GLDS16(Bh + (size_t)(n0 + row) * K + k0 + scol, &Bs[bi * 512 + l * 8]);
    }
    __syncthreads();
    #pragma unroll
    for (int kk = 0; kk < 64; kk += 32) {
      bf16x8 a[4], b[4];
      #pragma unroll
      for (int f = 0; f < 4; ++f)
        b[f] = *(const bf16x8*)&Bs[(wc * 64 + f * 16 + fr) * 64 + kk + fk];
      #pragma unroll
      for (int f = 0; f < 4; ++f)
        a[f] = *(const bf16x8*)&As[(wr * 64 + f * 16 + fr) * 64 + kk + fk];
      #pragma unroll
      for (int i = 0; i < 4; ++i)
        #pragma unroll
        for (int j = 0; j < 4; ++j)
          acc[i][j] = __builtin_amdgcn_mfma_f32_16x16x32_bf16(
              a[i], b[j], acc[i][j], 0, 0, 0);
    }
  }
  const int orow = (l >> 4) * 4;
  const int ocol = l & 15;
  if constexpr (EPI == 0 || EPI == 2) {
    unsigned short* Cw = (unsigned short*)Cv;
    #pragma unroll
    for (int i = 0; i < 4; ++i)
      #pragma unroll
      for (int j = 0; j < 4; ++j)
        #pragma unroll
        for (int r = 0; r < 4; ++r) {
          const int m = m0 + wr * 64 + i * 16 + orow + r;
          const int n = n0 + wc * 64 + j * 16 + ocol;
          float vv = acc[i][j][r];
          if constexpr (EPI == 2) {
            vv += bias[n];
            vv = (vv > 20.f) ? vv : log1pf(__expf(vv));
          }
          Cw[(size_t)m * ldc + n] = rnd_bf16(vv);
        }
  } else {
    float* Cw = (float*)Cv + (size_t)kz * M * ldc;
    #pragma unroll
    for (int i = 0; i < 4; ++i)
      #pragma unroll
      for (int j = 0; j < 4; ++j)
        #pragma unroll
        for (int r = 0; r < 4; ++r) {
          const int m = m0 + wr * 64 + i * 16 + orow + r;
          const int n = n0 + wc * 64 + j * 16 + ocol;
          Cw[(size_t)m * ldc + n] = acc[i][j][r];
        }
  }
}

// ---- x_proj split-K (bf16 A) ------------------------------------------------
__global__ __launch_bounds__(256) void sgemm_splitk_k(
    const unsigned short* __restrict__ A, const float* __restrict__ B,
    float* __restrict__ part) {
  __shared__ float As[32][64 + 4];
  __shared__ float Bs[32][32 + 4];
  const int tid = threadIdx.x;
  const int n0 = blockIdx.x * 32;
  const int m0 = blockIdx.y * 64;
  const int kz = blockIdx.z;
  const int tn = (tid & 15) * 2;
  const int tm = (tid >> 4) * 4;
  float acc[4][2] = {};
  for (int kb = 0; kb < 256; kb += 32) {
    const int k0 = kz * 256 + kb;
    {
      int r = tid >> 2, c8 = (tid & 3) * 8;
      us8 u = *(const us8*)(A + (size_t)(m0 + r) * D_INNER + k0 + c8);
      #pragma unroll
      for (int j = 0; j < 8; j++) As[c8 + j][r] = b2f((unsigned short)u[j]);
    }
    {
      int r = tid >> 3, c4 = tid & 7;
      float4 v = *(const float4*)(B + (size_t)(n0 + r) * D_INNER + k0 + c4 * 4);
      Bs[c4*4+0][r] = v.x; Bs[c4*4+1][r] = v.y;
      Bs[c4*4+2][r] = v.z; Bs[c4*4+3][r] = v.w;
    }
    __syncthreads();
    #pragma unroll
    for (int k = 0; k < 32; k++) {
      float a[4], bf[2];
      #pragma unroll
      for (int i = 0; i < 4; i++) a[i] = As[k][tm + i];
      bf[0] = Bs[k][tn]; bf[1] = Bs[k][tn + 1];
      #pragma unroll
      for (int i = 0; i < 4; i++) {
        acc[i][0] = fmaf(a[i], bf[0], acc[i][0]);
        acc[i][1] = fmaf(a[i], bf[1], acc[i][1]);
      }
    }
    __syncthreads();
  }
  float* p = part + (size_t)kz * BL * 96;
  #pragma unroll
  for (int i = 0; i < 4; i++) {
    const int m = m0 + tm + i;
    p[(size_t)m * 96 + n0 + tn]     = acc[i][0];
    p[(size_t)m * 96 + n0 + tn + 1] = acc[i][1];
  }
}

// reduce KS partials; split: cols 0..63 -> bf16 dtr, 64..95 -> fp32 bc[BL][32]
__global__ __launch_bounds__(256) void xproj_reduce_k(
    const float* __restrict__ part, unsigned short* __restrict__ dtr,
    float* __restrict__ bc) {
  const int i = blockIdx.x * 256 + threadIdx.x;   // over BL*96
  const int m = i / 96, col = i % 96;
  float s = 0.f;
  #pragma unroll
  for (int k = 0; k < KS; k++) s += part[(size_t)k * BL * 96 + i];
  if (col < DT_RANK) dtr[(size_t)m * DT_RANK + col] = rnd_bf16(s);
  else               bc[(size_t)m * 32 + (col - DT_RANK)] = s;
}

// ------ causal depthwise conv + SiLU, bf16 in / bf16 out ----------------------
__global__ __launch_bounds__(256) void conv_silu_k(
    const unsigned short* __restrict__ xz,
    const float* __restrict__ cw, const float* __restrict__ cb,
    unsigned short* __restrict__ xc) {
  const int gid = blockIdx.x * 256 + threadIdx.x;
  const int c4 = (gid & (D_INNER / 4 - 1)) << 2;
  const int row = gid >> 9;
  const int l = row & (LL - 1);
  const unsigned short* base = xz + (size_t)row * (2 * D_INNER) + c4;
  const float4 w0 = *(const float4*)(cw + (c4 + 0) * 4);
  const float4 w1 = *(const float4*)(cw + (c4 + 1) * 4);
  const float4 w2 = *(const float4*)(cw + (c4 + 2) * 4);
  const float4 w3 = *(const float4*)(cw + (c4 + 3) * 4);
  float4 acc = *(const float4*)(cb + c4);
  ushort4 uv = *(const ushort4*)base;
  acc.x = fmaf(w0.w, b2f(uv.x), acc.x); acc.y = fmaf(w1.w, b2f(uv.y), acc.y);
  acc.z = fmaf(w2.w, b2f(uv.z), acc.z); acc.w = fmaf(w3.w, b2f(uv.w), acc.w);
  if (l >= 1) {
    uv = *(const ushort4*)(base - 2 * D_INNER);
    acc.x = fmaf(w0.z, b2f(uv.x), acc.x); acc.y = fmaf(w1.z, b2f(uv.y), acc.y);
    acc.z = fmaf(w2.z, b2f(uv.z), acc.z); acc.w = fmaf(w3.z, b2f(uv.w), acc.w);
  }
  if (l >= 2) {
    uv = *(const ushort4*)(base - 4 * D_INNER);
    acc.x = fmaf(w0.y, b2f(uv.x), acc.x); acc.y = fmaf(w1.y, b2f(uv.y), acc.y);
    acc.z = fmaf(w2.y, b2f(uv.z), acc.z); acc.w = fmaf(w3.y, b2f(uv.w), acc.w);
  }
  if (l >= 3) {
    uv = *(const ushort4*)(base - 6 * D_INNER);
    acc.x = fmaf(w0.x, b2f(uv.x), acc.x); acc.y = fmaf(w1.x, b2f(uv.y), acc.y);
    acc.z = fmaf(w2.x, b2f(uv.z), acc.z); acc.w = fmaf(w3.x, b2f(uv.w), acc.w);
  }
  ushort4 o4;
  o4.x = rnd_bf16(acc.x / (1.f + __expf(-acc.x)));
  o4.y = rnd_bf16(acc.y / (1.f + __expf(-acc.y)));
  o4.z = rnd_bf16(acc.z / (1.f + __expf(-acc.z)));
  o4.w = rnd_bf16(acc.w / (1.f + __expf(-acc.w)));
  *(ushort4*)(xc + (size_t)row * D_INNER + c4) = o4;
}

// w-power helper: P[n] = w^(n+1), depth-4 multiply tree
__device__ inline void wpowers(float w1, float* P) {
  const float w2 = w1 * w1, w3 = w2 * w1, w4 = w2 * w2;
  const float w5 = w4 * w1, w6 = w4 * w2, w7 = w4 * w3, w8 = w4 * w4;
  P[0] = w1;  P[1] = w2;  P[2] = w3;  P[3] = w4;
  P[4] = w5;  P[5] = w6;  P[6] = w7;  P[7] = w8;
  P[8]  = w8 * w1;  P[9]  = w8 * w2;  P[10] = w8 * w3;  P[11] = w8 * w4;
  P[12] = w8 * w5;  P[13] = w8 * w6;  P[14] = w8 * w7;  P[15] = w8 * w8;
}

// ------- chunked selective scan, pass 1 (bf16 dt/xc, bc stride 32) ------------
__global__ __launch_bounds__(256) void scan_pass1_k(
    const unsigned short* __restrict__ dt, const unsigned short* __restrict__ xc,
    const float* __restrict__ bc, const float* __restrict__ A_log,
    float* __restrict__ hend, float* __restrict__ sumdt) {
  const int c = blockIdx.x * 256 + threadIdx.x;
  const int k = blockIdx.y;
  const int b = blockIdx.z;
  float Ac[D_STATE];
  bool fast = true;
  #pragma unroll
  for (int n = 0; n < D_STATE; n++) {
    Ac[n] = -__expf(A_log[c * D_STATE + n]);
    fast = fast && (fabsf(Ac[n] + (float)(n + 1)) <= 4e-6f * (float)(n + 1));
  }
  float h[D_STATE] = {};
  float sd = 0.f;
  const size_t r0 = (size_t)b * LL + (size_t)k * CLEN;
  const unsigned short* dtp = dt + r0 * D_INNER + c;
  const unsigned short* xcp = xc + r0 * D_INNER + c;
  const float* Bp  = bc + r0 * 32;

  float dtv = b2f(dtp[0]);
  float xv  = b2f(xcp[0]);
  float4 B0 = *(const float4*)(Bp + 0);
  float4 B1 = *(const float4*)(Bp + 4);
  float4 B2 = *(const float4*)(Bp + 8);
  float4 B3 = *(const float4*)(Bp + 12);
  if (fast) {
    for (int l = 0; l < CLEN; l++) {
      const int lp = (l + 1 < CLEN) ? l + 1 : l;
      const float dtv2 = b2f(dtp[(size_t)lp * D_INNER]);
      const float xv2  = b2f(xcp[(size_t)lp * D_INNER]);
      const float4 B0n = *(const float4*)(Bp + (size_t)lp * 32 + 0);
      const float4 B1n = *(const float4*)(Bp + (size_t)lp * 32 + 4);
      const float4 B2n = *(const float4*)(Bp + (size_t)lp * 32 + 8);
      const float4 B3n = *(const float4*)(Bp + (size_t)lp * 32 + 12);
      sd += dtv;
      const float dx = dtv * xv;
      float P[D_STATE];
      wpowers(__expf(-dtv), P);
      const float Bv[D_STATE] = {B0.x,B0.y,B0.z,B0.w, B1.x,B1.y,B1.z,B1.w,
                                 B2.x,B2.y,B2.z,B2.w, B3.x,B3.y,B3.z,B3.w};
      #pragma unroll
      for (int n = 0; n < D_STATE; n++)
        h[n] = fmaf(P[n], h[n], dx * Bv[n]);
      dtv = dtv2; xv = xv2; B0 = B0n; B1 = B1n; B2 = B2n; B3 = B3n;
    }
  } else {
    for (int l = 0; l < CLEN; l++) {
      const int lp = (l + 1 < CLEN) ? l + 1 : l;
      const float dtv2 = b2f(dtp[(size_t)lp * D_INNER]);
      const float xv2  = b2f(xcp[(size_t)lp * D_INNER]);
      const float4 B0n = *(const float4*)(Bp + (size_t)lp * 32 + 0);
      const float4 B1n = *(const float4*)(Bp + (size_t)lp * 32 + 4);
      const float4 B2n = *(const float4*)(Bp + (size_t)lp * 32 + 8);
      const float4 B3n = *(const float4*)(Bp + (size_t)lp * 32 + 12);
      sd += dtv;
      const float dx = dtv * xv;
      const float Bv[D_STATE] = {B0.x,B0.y,B0.z,B0.w, B1.x,B1.y,B1.z,B1.w,
                                 B2.x,B2.y,B2.z,B2.w, B3.x,B3.y,B3.z,B3.w};
      #pragma unroll
      for (int n = 0; n < D_STATE; n++)
        h[n] = fmaf(__expf(dtv * Ac[n]), h[n], dx * Bv[n]);
      dtv = dtv2; xv = xv2; B0 = B0n; B1 = B1n; B2 = B2n; B3 = B3n;
    }
  }
  float* he = hend + (((size_t)(b * CH + k) * D_INNER + c) << 4);
  #pragma unroll
  for (int n = 0; n < D_STATE; n += 4)
    *(float4*)(he + n) = make_float4(h[n], h[n+1], h[n+2], h[n+3]);
  sumdt[(size_t)(b * CH + k) * D_INNER + c] = sd;
}

// ------- chunked scan fixup ---------------------------------------------------
__global__ __launch_bounds__(256) void scan_fix_k(
    float* __restrict__ hend, const float* __restrict__ sumdt,
    const float* __restrict__ A_log) {
  const int gid = blockIdx.x * 256 + threadIdx.x;
  const int n = gid & 15;
  const int c = (gid >> 4) & (D_INNER - 1);
  const int b = gid >> 15;
  const float Ac = -__expf(A_log[c * D_STATE + n]);
  float hrun = 0.f;
  for (int k = 0; k < CH; k++) {
    const size_t base = (size_t)(b * CH + k) * D_INNER + c;
    const float sd = sumdt[base];
    float* hp = hend + (base << 4) + n;
    const float tmp = *hp;
    *hp = hrun;
    hrun = fmaf(__expf(Ac * sd), hrun, tmp);
  }
}

// ------- chunked scan pass 3 (bc stride 32, fast w-power path) -----------------
__global__ __launch_bounds__(256) void scan_pass3_k(
    const unsigned short* __restrict__ dt, const unsigned short* __restrict__ xc,
    const float* __restrict__ bc, const unsigned short* __restrict__ xz,
    const float* __restrict__ h0, const float* __restrict__ A_log,
    const float* __restrict__ Dp, unsigned short* __restrict__ yh) {
  const int c = blockIdx.x * 256 + threadIdx.x;
  const int k = blockIdx.y;
  const int b = blockIdx.z;
  float Ac[D_STATE];
  bool fast = true;
  #pragma unroll
  for (int n = 0; n < D_STATE; n++) {
    Ac[n] = -__expf(A_log[c * D_STATE + n]);
    fast = fast && (fabsf(Ac[n] + (float)(n + 1)) <= 4e-6f * (float)(n + 1));
  }
  const float Dv = Dp[c];
  float h[D_STATE];
  const float* hp = h0 + (((size_t)(b * CH + k) * D_INNER + c) << 4);
  #pragma unroll
  for (int n = 0; n < D_STATE; n += 4) {
    const float4 v = *(const float4*)(hp + n);
    h[n] = v.x; h[n+1] = v.y; h[n+2] = v.z; h[n+3] = v.w;
  }
  const size_t r0 = (size_t)b * LL + (size_t)k * CLEN;
  const unsigned short* dtp = dt + r0 * D_INNER + c;
  const unsigned short* xcp = xc + r0 * D_INNER + c;
  const float* Bp  = bc + r0 * 32;
  const unsigned short* zp = xz + r0 * (size_t)(2 * D_INNER) + D_INNER + c;
  unsigned short* yhp = yh + r0 * D_INNER + c;

  float dtv = b2f(dtp[0]);
  float xv  = b2f(xcp[0]);
  float zv  = b2f(zp[0]);
  float4 B0 = *(const float4*)(Bp + 0);
  float4 B1 = *(const float4*)(Bp + 4);
  float4 B2 = *(const float4*)(Bp + 8);
  float4 B3 = *(const float4*)(Bp + 12);
  float4 C0 = *(const float4*)(Bp + 16);
  float4 C1 = *(const float4*)(Bp + 20);
  float4 C2 = *(const float4*)(Bp + 24);
  float4 C3 = *(const float4*)(Bp + 28);
  if (fast) {
    for (int l = 0; l < CLEN; l++) {
      const int lp = (l + 1 < CLEN) ? l + 1 : l;
      const float dtv2 = b2f(dtp[(size_t)lp * D_INNER]);
      const float xv2  = b2f(xcp[(size_t)lp * D_INNER]);
      const float zv2  = b2f(zp[(size_t)lp * 2 * D_INNER]);
      const float4 B0n = *(const float4*)(Bp + (size_t)lp * 32 + 0);
      const float4 B1n = *(const float4*)(Bp + (size_t)lp * 32 + 4);
      const float4 B2n = *(const float4*)(Bp + (size_t)lp * 32 + 8);
      const float4 B3n = *(const float4*)(Bp + (size_t)lp * 32 + 12);
      const float4 C0n = *(const float4*)(Bp + (size_t)lp * 32 + 16);
      const float4 C1n = *(const float4*)(Bp + (size_t)lp * 32 + 20);
      const float4 C2n = *(const float4*)(Bp + (size_t)lp * 32 + 24);
      const float4 C3n = *(const float4*)(Bp + (size_t)lp * 32 + 28);
      const float dx = dtv * xv;
      float P[D_STATE];
      wpowers(__expf(-dtv), P);
      const float Bv[D_STATE] = {B0.x,B0.y,B0.z,B0.w, B1.x,B1.y,B1.z,B1.w,
                                 B2.x,B2.y,B2.z,B2.w, B3.x,B3.y,B3.z,B3.w};
      const float Cv[D_STATE] = {C0.x,C0.y,C0.z,C0.w, C1.x,C1.y,C1.z,C1.w,
                                 C2.x,C2.y,C2.z,C2.w, C3.x,C3.y,C3.z,C3.w};
      float y = 0.f;
      #pragma unroll
      for (int n = 0; n < D_STATE; n++) {
        h[n] = fmaf(P[n], h[n], dx * Bv[n]);
        y = fmaf(h[n], Cv[n], y);
      }
      y = fmaf(xv, Dv, y);
      y *= zv / (1.f + __expf(-zv));
      yhp[(size_t)l * D_INNER] = rnd_bf16(y);
      dtv = dtv2; xv = xv2; zv = zv2;
      B0 = B0n; B1 = B1n; B2 = B2n; B3 = B3n;
      C0 = C0n; C1 = C1n; C2 = C2n; C3 = C3n;
    }
  } else {
    for (int l = 0; l < CLEN; l++) {
      const int lp = (l + 1 < CLEN) ? l + 1 : l;
      const float dtv2 = b2f(dtp[(size_t)lp * D_INNER]);
      const float xv2  = b2f(xcp[(size_t)lp * D_INNER]);
      const float zv2  = b2f(zp[(size_t)lp * 2 * D_INNER]);
      const float4 B0n = *(const float4*)(Bp + (size_t)lp * 32 + 0);
      const float4 B1n = *(const float4*)(Bp + (size_t)lp * 32 + 4);
      const float4 B2n = *(const float4*)(Bp + (size_t)lp * 32 + 8);
      const float4 B3n = *(const float4*)(Bp + (size_t)lp * 32 + 12);
      const float4 C0n = *(const float4*)(Bp + (size_t)lp * 32 + 16);
      const float4 C1n = *(const float4*)(Bp + (size_t)lp * 32 + 20);
      const float4 C2n = *(const float4*)(Bp + (size_t)lp * 32 + 24);
      const float4 C3n = *(const float4*)(Bp + (size_t)lp * 32 + 28);
      const float dx = dtv * xv;
      const float Bv[D_STATE] = {B0.x,B0.y,B0.z,B0.w, B1.x,B1.y,B1.z,B1.w,
                                 B2.x,B2.y,B2.z,B2.w, B3.x,B3.y,B3.z,B3.w};
      const float Cv[D_STATE] = {C0.x,C0.y,C0.z,C0.w, C1.x,C1.y,C1.z,C1.w,
                                 C2.x,C2.y,C2.z,C2.w, C3.x,C3.y,C3.z,C3.w};
      float y = 0.f;
      #pragma unroll
      for (int n = 0; n < D_STATE; n++) {
        h[n] = fmaf(__expf(dtv * Ac[n]), h[n], dx * Bv[n]);
        y = fmaf(h[n], Cv[n], y);
      }
      y = fmaf(xv, Dv, y);
      y *= zv / (1.f + __expf(-zv));
      yhp[(size_t)l * D_INNER] = rnd_bf16(y);
      dtv = dtv2; xv = xv2; zv = zv2;
      B0 = B0n; B1 = B1n; B2 = B2n; B3 = B3n;
      C0 = C0n; C1 = C1n; C2 = C2n; C3 = C3n;
    }
  }
}

// ---------------- mean pool over L, two-stage ---------------------------------
__global__ __launch_bounds__(256) void pool1_k(const float* __restrict__ h,
    float* __restrict__ pp) {
  const int d = blockIdx.x * 256 + threadIdx.x;
  const int b = blockIdx.y;
  const int seg = blockIdx.z;
  float s = 0.f;
  const size_t base = (size_t)b * LL + (size_t)seg * 64;
  for (int l = 0; l < 64; l++) s += h[(base + l) * D_MODEL + d];
  pp[((size_t)(b * 16 + seg)) * D_MODEL + d] = s;
}
__global__ __launch_bounds__(256) void pool2_k(const float* __restrict__ pp,
    float* __restrict__ pooled) {
  const int d = blockIdx.x * 256 + threadIdx.x;
  const int b = blockIdx.y;
  float s = 0.f;
  #pragma unroll
  for (int k = 0; k < 16; k++) s += pp[((size_t)(b * 16 + k)) * D_MODEL + d];
  pooled[b * D_MODEL + d] = s * (1.f / LL);
}

// ---------------- classifier head --------------------------------------------
__global__ __launch_bounds__(64) void head_k(const float* __restrict__ pooled,
    const float* __restrict__ hw, const float* __restrict__ hb,
    float* __restrict__ out) {
  const int b = blockIdx.x / N_CLASSES;
  const int j = blockIdx.x % N_CLASSES;
  float s = 0.f;
  for (int k = threadIdx.x; k < D_MODEL; k += 64)
    s = fmaf(pooled[b * D_MODEL + k], hw[j * D_MODEL + k], s);
  #pragma unroll
  for (int o = 32; o; o >>= 1) s += __shfl_down(s, o);
  if (threadIdx.x == 0) out[b * N_CLASSES + j] = s + hb[j];
}

extern "C" void kernel_launch(void* const* d_in, const int* in_sizes, int n_in,
                              void* d_out, int out_size, void* d_ws, size_t ws_size,
                              hipStream_t stream) {
  const float* x0    = (const float*)d_in[0];
  const float* ln1w  = (const float*)d_in[1];
  const float* ln1b  = (const float*)d_in[2];
  const float* inw   = (const float*)d_in[3];
  const float* convw = (const float*)d_in[4];
  const float* convb = (const float*)d_in[5];
  const float* xpw   = (const float*)d_in[6];
  const float* dtpw  = (const float*)d_in[7];
  const float* dtpb  = (const float*)d_in[8];
  const float* Alog  = (const float*)d_in[9];
  const float* Dp    = (const float*)d_in[10];
  const float* outw  = (const float*)d_in[11];
  const float* normw = (const float*)d_in[12];
  const float* normb = (const float*)d_in[13];
  const float* headw = (const float*)d_in[14];
  const float* headb = (const float*)d_in[15];

  float* ws = (float*)d_ws;
  size_t f = 0;
  float* X      = ws + f; f += (size_t)BL * D_MODEL;
  // --- opart overlay region: xzf (8.39M) + xcb (4.19M) + hend (4.19M)
  //     = exactly KSO*BL*D_MODEL = 16.78M floats; all three are dead when
  //     out_proj writes opart (after scan_pass3) and reborn next layer.
  float* xzf    = ws + f; f += (size_t)BL * D_INNER;                 // bf16 xz
  unsigned short* xcb = (unsigned short*)(ws + f);
  f += (size_t)BL * D_INNER / 2;                                     // bf16 xc
  float* hend   = ws + f; f += (size_t)BB * CH * D_INNER * D_STATE;
  float* opart  = xzf;                                               // overlay
  // --- end overlay region
  float* bc     = ws + f; f += (size_t)BL * 32;
  float* dty    = ws + f; f += (size_t)BL * D_INNER;
  float* pooled = ws + f; f += 4096;
  float* pooldp = ws + f; f += (size_t)16 * BB * D_MODEL;
  float* xpart  = ws + f; f += (size_t)KS * BL * 96;
  unsigned short* hh  = (unsigned short*)(ws + f); f += (size_t)BL * D_MODEL / 2;
  unsigned short* yh  = (unsigned short*)(ws + f); f += (size_t)BL * D_INNER / 2;
  unsigned short* dtr = (unsigned short*)(ws + f); f += (size_t)BL * DT_RANK / 2;
  unsigned short* wih = (unsigned short*)(ws + f);
  f += (size_t)N_LAYERS * 2 * D_INNER * D_MODEL / 2;
  unsigned short* woh = (unsigned short*)(ws + f);
  f += (size_t)N_LAYERS * D_MODEL * D_INNER / 2;
  unsigned short* wdt = (unsigned short*)(ws + f);
  f += (size_t)N_LAYERS * D_INNER * DT_RANK / 2;
  unsigned short* xz  = (unsigned short*)xzf;
  unsigned short* dtb = (unsigned short*)dty;
  float* sumdt = xpart;

  round_k<<<(N_LAYERS * 2 * D_INNER * D_MODEL) / 1024, 256, 0, stream>>>(inw, wih);
  round_k<<<(N_LAYERS * D_MODEL * D_INNER) / 1024, 256, 0, stream>>>(outw, woh);
  round_k<<<(N_LAYERS * D_INNER * DT_RANK) / 1024, 256, 0, stream>>>(dtpw, wdt);
  layernorm_bf16_k<<<BL, 256, 0, stream>>>(x0, ln1w, ln1b, hh);

  for (int layer = 0; layer < N_LAYERS; ++layer) {
    const unsigned short* wi = wih + (size_t)layer * 2 * D_INNER * D_MODEL;
    const unsigned short* wo = woh + (size_t)layer * D_MODEL * D_INNER;
    const unsigned short* wd = wdt + (size_t)layer * D_INNER * DT_RANK;
    // xz = h @ in_w^T : 4096x4096x1024, 256² pipeline, bf16 out, XCD remap
    mfma_gemm256_nt<0, 1, 1><<<dim3(16, 16), 512, 0, stream>>>(
        hh, wi, xz, BL, 2 * D_INNER, D_MODEL, 2 * D_INNER);
    conv_silu_k<<<(BL * D_INNER / 4) / 256, 256, 0, stream>>>(
        xz, convw + layer * D_INNER * D_CONV, convb + layer * D_INNER, xcb);
    sgemm_splitk_k<<<dim3(96 / 32, 4096 / 64, KS), 256, 0, stream>>>(
        xcb, xpw + (size_t)layer * 96 * D_INNER, xpart);
    xproj_reduce_k<<<(BL * 96) / 256, 256, 0, stream>>>(xpart, dtr, bc);
    mfma_gemm_nt<2, 1><<<dim3(2048 / 128, 4096 / 128), 256, 0, stream>>>(
        dtr, wd, dtb, BL, D_INNER, DT_RANK, D_INNER, dtpb + layer * D_INNER);
    scan_pass1_k<<<dim3(D_INNER / 256, CH, BB), 256, 0, stream>>>(
        dtb, xcb, bc, Alog + (size_t)layer * D_INNER * D_STATE, hend, sumdt);
    scan_fix_k<<<(BB * D_INNER * D_STATE) / 256, 256, 0, stream>>>(
        hend, sumdt, Alog + (size_t)layer * D_INNER * D_STATE);
    scan_pass3_k<<<dim3(D_INNER / 256, CH, BB), 256, 0, stream>>>(
        dtb, xcb, bc, xz, hend, Alog + (size_t)layer * D_INNER * D_STATE,
        Dp + layer * D_INNER, yh);
    // y @ out_w^T : 4096x1024x2048, 256² pipeline, split-K=4 fp32 partials
    // (opart overlays xz/xcb/hend — all dead here)
    mfma_gemm256_nt<1, KSO, 0><<<dim3(1024 / 256, 4096 / 256, KSO), 512, 0,
                                 stream>>>(
        yh, wo, opart, BL, D_MODEL, D_INNER, D_MODEL);
    const float* Xin = (layer == 0) ? x0 : X;
    if (layer + 1 < N_LAYERS) {
      oreduce_ln_k<0><<<BL, 256, 0, stream>>>(
          opart, Xin, X, ln1w + (layer + 1) * D_MODEL,
          ln1b + (layer + 1) * D_MODEL, hh);
    } else {
      oreduce_ln_k<1><<<BL, 256, 0, stream>>>(opart, Xin, X, normw, normb, dty);
    }
  }

  pool1_k<<<dim3(D_MODEL / 256, BB, 16), 256, 0, stream>>>(dty, pooldp);
  pool2_k<<<dim3(D_MODEL / 256, BB), 256, 0, stream>>>(pooldp, pooled);
  head_k<<<BB * N_CLASSES, 64, 0, stream>>>(pooled, headw, headb, (float*)d_out);
}